// Round 12
// baseline (796.245 us; speedup 1.0000x reference)
//
#include <hip/hip_runtime.h>
#include <hip/hip_bf16.h>

typedef unsigned short u16;
typedef unsigned int u32;
typedef __attribute__((ext_vector_type(8))) short bf16x8;
typedef __attribute__((ext_vector_type(4))) float f32x4;
typedef __attribute__((address_space(3))) u32 lds_u32;
typedef const __attribute__((address_space(1))) u32 glb_u32;

#define H_ 128
#define W_ 128
#define PX 16384
#define PH 130

__device__ __forceinline__ float b2f(u16 h){ u32 u = ((u32)h)<<16; return __uint_as_float(u); }
__device__ __forceinline__ u16 f2b(float f){
  u32 u = __float_as_uint(f);
  u32 r = (u + 0x7fffu + ((u>>16)&1u)) >> 16;
  return (u16)r;
}
// mode: 1 = inputs are float32, 0 = inputs are bf16
__device__ __forceinline__ float ldv(const void* p, long i, int m){
  return m ? ((const float*)p)[i] : b2f(((const u16*)p)[i]);
}
__device__ __forceinline__ void gload16(const u16* g, u16* l){
  __builtin_amdgcn_global_load_lds((glb_u32*)g, (lds_u32*)l, 16, 0, 0);
}

// ---------------- dtype autodetect ----------------
__global__ void k_detect(const u32* __restrict__ xw, u32* __restrict__ flag){
  __shared__ int cnt[256];
  const int t = threadIdx.x;
  int c = 0;
  #pragma unroll
  for (int i=0;i<4;i++){
    const u32 w = xw[t*4+i];
    const u32 e = ((w & 0xFFFFu) >> 7) & 0xFF;
    if (e >= 90 && e <= 140) c++;     // bf16 low-half exponent range for N(0,1)
  }
  cnt[t] = c; __syncthreads();
  for (int s=128;s>0;s>>=1){ if (t<s) cnt[t]+=cnt[t+s]; __syncthreads(); }
  if (t==0) flag[0] = (cnt[0] < 512) ? 1u : 0u;   // few hits -> f32 data
}

// ---------------- border-zero for h1t pads (replaces 34.6MB memset) ----------------
__global__ void k_zpad(u16* __restrict__ h1t){
  const int p = blockIdx.x;            // 8 planes: br = p>>1, n = p&1
  u16* base = h1t + (long)p*2163200L;  // [130][130][128]
  const int t = threadIdx.x;
  const int4 z = make_int4(0,0,0,0);
  for (int idx=t; idx<8256; idx+=256){
    long off;
    if (idx < 2080)       off = (long)idx*8;                                   // row 0
    else if (idx < 4160)  off = 2146560L + (long)(idx-2080)*8;                 // row 129
    else if (idx < 6208){ const int r = 1 + (idx-4160)/16, w = (idx-4160)%16;  // col 0
                          off = (long)r*16640 + w*8; }
    else {                const int r = 1 + (idx-6208)/16, w = (idx-6208)%16;  // col 129
                          off = (long)r*16640 + 16512 + w*8; }
    *(int4*)(base + off) = z;
  }
}

// ---------------- implicit-GEMM conv kernel (conv1 / se / 1x1) ----------------
// EPI: 0=bias, 1=bias+relu, 2=bias+sigmoid, 3=(bias)*sw+lrelu ->NHWC,
//      4=EPI3 math then fused residual add + NCHW write to outF
template<int CIN, int NTAPS, int EPI>
__global__ __launch_bounds__(256, 2)
void k_convgemm(const u16* __restrict__ inp, const u16* __restrict__ wp,
                const u16* __restrict__ bias, const u16* __restrict__ swp,
                u16* __restrict__ outp, int nbco,
                long in_br, long w_br, int bias_br, long out_br,
                long in_n, int in_row, int in_x0,
                long out_n, long out_y, int out_px, int out_x0,
                long sw_n, int sw_y,
                const void* __restrict__ xres, const u32* __restrict__ flagp,
                void* __restrict__ outF)
{
  __shared__ u16 ls[17408];          // A:[0,8192) B:[8192,16384); epilogue tile [128][136]
  u16* lsA = ls;
  u16* lsB = ls + 8192;

  const int bx  = blockIdx.x;
  // XCD-aware y swizzle for the 3x3 convs (halo reuse in per-XCD L2); grid.x==128
  const int y   = (NTAPS==9) ? (((bx&7)<<4) | (bx>>3)) : bx;
  const int br  = blockIdx.y / nbco;
  const int cb  = blockIdx.y - br*nbco;
  const int n   = blockIdx.z;
  const int tid = threadIdx.x;
  const int wave = tid >> 6, lane = tid & 63;
  const int l16 = lane & 15, lg = lane >> 4;
  const int chw = (wave >> 1) * 64;   // co half
  const int phw = (wave & 1) * 64;    // px half

  const u16* inb   = inp + (long)br*in_br + (long)n*in_n + in_x0 + (long)y*in_row;
  const u16* wb    = wp  + (long)br*w_br + (long)cb*128*(NTAPS*CIN);
  const u16* biasb = bias + (long)br*bias_br + cb*128;
  u16* outb = outp + (long)br*out_br + (long)n*out_n + out_x0 + (long)y*out_y;

  f32x4 acc[4][4];
  #pragma unroll
  for (int m=0;m<4;m++)
    #pragma unroll
    for (int q=0;q<4;q++) acc[m][q] = (f32x4){0.f,0.f,0.f,0.f};

  constexpr int NSTEP = NTAPS*(CIN/64);
  #pragma unroll
  for (int step=0; step<NSTEP; ++step){
    const int tap = step/(CIN/64);
    const int k0  = (step - tap*(CIN/64))*64;
    const int dy = (NTAPS==1)?0:(tap/3-1);
    const int dx = (NTAPS==1)?0:(tap%3-1);
    const u16* wsrc = wb  + tap*CIN + k0;
    const u16* bsrc = inb + (long)dy*in_row + dx*CIN + k0;
    #pragma unroll
    for (int i=0;i<4;i++){
      const int idx = (wave*4+i)*64 + lane;
      const int r = idx>>3, c = idx&7;
      const int cc = c ^ (r&7);
      gload16(wsrc + (long)r*(NTAPS*CIN) + cc*8, lsA + (wave*4+i)*512);
    }
    #pragma unroll
    for (int i=0;i<4;i++){
      const int idx = (wave*4+i)*64 + lane;
      const int r = idx>>3, c = idx&7;
      const int cc = c ^ (r&7);
      gload16(bsrc + (long)r*CIN + cc*8, lsB + (wave*4+i)*512);
    }
    __syncthreads();
    #pragma unroll
    for (int kk=0;kk<2;kk++){
      bf16x8 af[4], bfr[4];
      const int kc = kk*4 + lg;
      #pragma unroll
      for (int m=0;m<4;m++){
        const int r = chw + m*16 + l16;
        af[m] = *(const bf16x8*)(lsA + r*64 + ((kc ^ (r&7))<<3));
      }
      #pragma unroll
      for (int q=0;q<4;q++){
        const int r = phw + q*16 + l16;
        bfr[q] = *(const bf16x8*)(lsB + r*64 + ((kc ^ (r&7))<<3));
      }
      #pragma unroll
      for (int m=0;m<4;m++)
        #pragma unroll
        for (int q=0;q<4;q++)
          acc[m][q] = __builtin_amdgcn_mfma_f32_16x16x32_bf16(af[m], bfr[q], acc[m][q], 0,0,0);
    }
    __syncthreads();
  }

  // epilogue: acc -> LDS tile [px 128][co 136]
  #pragma unroll
  for (int m=0;m<4;m++){
    const int co = chw + m*16 + lg*4;
    const ushort4 bb = *(const ushort4*)(biasb + co);
    const float bv0=b2f(bb.x), bv1=b2f(bb.y), bv2=b2f(bb.z), bv3=b2f(bb.w);
    #pragma unroll
    for (int q=0;q<4;q++){
      const int px = phw + q*16 + l16;
      float v0 = acc[m][q][0] + bv0;
      float v1 = acc[m][q][1] + bv1;
      float v2 = acc[m][q][2] + bv2;
      float v3 = acc[m][q][3] + bv3;
      if (EPI==1){
        v0=fmaxf(v0,0.f); v1=fmaxf(v1,0.f); v2=fmaxf(v2,0.f); v3=fmaxf(v3,0.f);
      } else if (EPI==2){
        v0 = 1.f/(1.f+__expf(-v0)); v1 = 1.f/(1.f+__expf(-v1));
        v2 = 1.f/(1.f+__expf(-v2)); v3 = 1.f/(1.f+__expf(-v3));
      } else if (EPI==3 || EPI==4){
        const ushort4 sv = *(const ushort4*)(swp + (long)n*sw_n + (long)y*sw_y + (long)px*256 + cb*128 + co);
        v0 *= b2f(sv.x); v1 *= b2f(sv.y); v2 *= b2f(sv.z); v3 *= b2f(sv.w);
        v0 = v0>=0.f? v0 : 0.2f*v0;  v1 = v1>=0.f? v1 : 0.2f*v1;
        v2 = v2>=0.f? v2 : 0.2f*v2;  v3 = v3>=0.f? v3 : 0.2f*v3;
      }
      ushort4 ov; ov.x=f2b(v0); ov.y=f2b(v1); ov.z=f2b(v2); ov.w=f2b(v3);
      *(ushort4*)(ls + px*136 + co) = ov;
    }
  }
  __syncthreads();
  if (EPI == 4){
    // fused: out[n][c][y][:] = x + dx3, NCHW, coalesced per co row
    const int m2 = (int)flagp[0];
    const int co = tid>>1, hf2 = tid&1;
    const long xoff = (((long)n*256 + cb*128 + co)*H_ + y)*W_ + hf2*64;
    const u16* lrow = ls + (hf2*64)*136 + co;
    if (m2){
      const float* xf = (const float*)xres;
      float* of = (float*)outF;
      #pragma unroll
      for (int i=0;i<16;i++){
        const float4 xv = *(const float4*)(xf + xoff + i*4);
        float4 ov;
        ov.x = xv.x + b2f(lrow[(i*4+0)*136]);
        ov.y = xv.y + b2f(lrow[(i*4+1)*136]);
        ov.z = xv.z + b2f(lrow[(i*4+2)*136]);
        ov.w = xv.w + b2f(lrow[(i*4+3)*136]);
        *(float4*)(of + xoff + i*4) = ov;
      }
    } else {
      const u16* xu = (const u16*)xres;
      u16* ou = (u16*)outF;
      #pragma unroll
      for (int i=0;i<8;i++){
        const bf16x8 xv = *(const bf16x8*)(xu + xoff + i*8);
        bf16x8 ov;
        #pragma unroll
        for (int e=0;e<8;e++)
          ov[e] = (short)f2b(b2f((u16)xv[e]) + b2f(lrow[(i*8+e)*136]));
        *(bf16x8*)(ou + xoff + i*8) = ov;
      }
    }
  } else {
    const int row = tid>>1, hf = tid&1;
    u16* og = outb + (long)row*out_px + cb*128 + hf*64;
    #pragma unroll
    for (int i=0;i<8;i++)
      *(int4*)(og + i*8) = *(const int4*)(ls + row*136 + hf*64 + i*8);
  }
}

// ---------------- FUSED gw-conv + BN-affine + dynamic depthwise (v6u) ----------------
// 256 threads. Block = 144co x 128px (16 channels), BK=64, 18 K-steps FULLY UNROLLED
// (tap/dy/dx compile-time; staging addresses CSE into ~9 hoisted per-thread offsets).
// 4 waves as 1M x 4N: wave tile 144co x 32px -> acc[9][2] = 72 AGPR; VGPR target <=98
// -> 3 waves/SIMD; LDS 38,016 B -> 3 blocks/CU (~12 waves/CU).
// XCD swizzle: y = (bx&7)*16 + bx>>3.
__global__ __launch_bounds__(256, 2)
void k_convdw(const u16* __restrict__ h1,      // padded [n][130][130][128]
              const u16* __restrict__ wp,      // [2304][9][128]
              const u16* __restrict__ bp,      // [2304] (co''=c*9+k order)
              const u16* __restrict__ xh,      // padded [n][130][130][256] (pre-BN act)
              const float2* __restrict__ ss,   // BN (scale, shift)
              u16* __restrict__ dd)            // [n][16384][256]
{
  __shared__ u16 ls[19008];   // 38,016 B; staging A[0,9216) B[9216,17408); ct[144][132] overlays
  u16* lsA = ls;
  u16* lsB = ls + 9216;

  const int bx = blockIdx.x, mt = blockIdx.y, n = blockIdx.z;   // mt in [0,16)
  const int y = ((bx&7)<<4) | (bx>>3);      // XCD-band swizzle (bijective, 128%8==0)
  const int tid = threadIdx.x;
  const int wave = tid >> 6, lane = tid & 63;
  const int l16 = lane & 15, lg = lane >> 4;
  const int wn = wave * 32;           // px offset of wave

  const u16* wb = wp + (long)mt*144*1152;
  const u16* inb = h1 + (((long)n*PH + (y+1))*PH + 1)*128;

  f32x4 acc[9][2];
  #pragma unroll
  for (int m=0;m<9;m++){ acc[m][0]=(f32x4){0,0,0,0}; acc[m][1]=(f32x4){0,0,0,0}; }

  #pragma unroll
  for (int s=0; s<18; ++s){
    const int tap = s >> 1;
    const int k0  = (s & 1) * 64;
    const int dy = tap/3 - 1, dx = tap%3 - 1;
    const u16* wsrc = wb + tap*128 + k0;
    const u16* bsrc = inb + ((long)dy*PH + dx)*128 + k0;
    // stage A: 144 rows x 64 ci = 1152 chunks (4 x 256 + 128)
    #pragma unroll
    for (int i=0;i<4;i++){
      const int g = i*256 + tid;
      const int r = g>>3, c = g&7, sp = c ^ (r&7);
      gload16(wsrc + (long)r*1152 + sp*8, lsA + g*8);
    }
    if (tid < 128){
      const int g = 1024 + tid;
      const int r = g>>3, c = g&7, sp = c ^ (r&7);
      gload16(wsrc + (long)r*1152 + sp*8, lsA + g*8);
    }
    // stage B: 128 px x 64 ci = 1024 chunks (4 x 256)
    #pragma unroll
    for (int i=0;i<4;i++){
      const int g = i*256 + tid;
      const int p = g>>3, c = g&7, sp = c ^ (p&7);
      gload16(bsrc + (long)p*128 + sp*8, lsB + g*8);
    }
    __syncthreads();
    #pragma unroll
    for (int kk=0;kk<2;kk++){
      const int kc = kk*4 + lg;
      bf16x8 bfr[2];
      #pragma unroll
      for (int q=0;q<2;q++){
        const int rb = wn + q*16 + l16;
        bfr[q] = *(const bf16x8*)(lsB + rb*64 + ((kc ^ (rb&7))<<3));
      }
      #pragma unroll
      for (int m=0;m<9;m++){
        const int ra = m*16 + l16;
        const bf16x8 a = *(const bf16x8*)(lsA + ra*64 + ((kc ^ (ra&7))<<3));
        acc[m][0] = __builtin_amdgcn_mfma_f32_16x16x32_bf16(a, bfr[0], acc[m][0], 0,0,0);
        acc[m][1] = __builtin_amdgcn_mfma_f32_16x16x32_bf16(a, bfr[1], acc[m][1], 0,0,0);
      }
    }
    __syncthreads();
  }

  // ---- epilogue 1: cw + bias -> ct[144][132] (all 4 waves, disjoint px) ----
  u16* ct = ls;
  #pragma unroll
  for (int m=0;m<9;m++){
    const int r0 = m*16 + lg*4;
    const ushort4 bb = *(const ushort4*)(bp + mt*144 + r0);
    const float bv0=b2f(bb.x), bv1=b2f(bb.y), bv2=b2f(bb.z), bv3=b2f(bb.w);
    #pragma unroll
    for (int q=0;q<2;q++){
      const int px = wn + q*16 + l16;
      ct[(r0+0)*132 + px] = f2b(acc[m][q][0] + bv0);
      ct[(r0+1)*132 + px] = f2b(acc[m][q][1] + bv1);
      ct[(r0+2)*132 + px] = f2b(acc[m][q][2] + bv2);
      ct[(r0+3)*132 + px] = f2b(acc[m][q][3] + bv3);
    }
  }
  __syncthreads();

  // ---- epilogue 2: depthwise. 256 threads: cl = tid&15 channel, xg = tid>>4 ----
  const int cl = tid & 15;
  const int c  = mt*16 + cl;
  const float2 sc = ss[c];
  const int xg = tid >> 4;
  #pragma unroll
  for (int i=0;i<8;i++){
    const int x = i*16 + xg;
    float a = 0.f;
    #pragma unroll
    for (int k=0;k<9;k++){
      const int ddy = k/3-1, ddx = k%3-1;
      const int gy = y+ddy, gx = x+ddx;
      if ((unsigned)gy < 128u && (unsigned)gx < 128u){
        const float xv = b2f(xh[(((long)n*PH + (gy+1))*PH + (gx+1))*256 + c]);
        const float w  = b2f(ct[(cl*9+k)*132 + x]);
        a += (xv*sc.x + sc.y) * w;
      }
    }
    dd[(((long)n*PX) + (long)y*W_ + x)*256 + c] = f2b(a);
  }
}

// ---------------- BN statistics (2-stage, deterministic) ----------------
__global__ void k_bnstat1(const u16* __restrict__ buf, float* __restrict__ part)
{
  const int wg = blockIdx.x;             // 256 = n*128 + y
  const int n = wg>>7, y = wg&127;
  const int c = threadIdx.x;
  const u16* p = buf + (((long)n*PH + (y+1))*PH + 1)*256 + c;
  float s=0.f, q=0.f;
  for (int x=0;x<128;x++){ float v = b2f(p[(long)x*256]); s+=v; q+=v*v; }
  float* o = part + ((long)wg*256 + c)*2;
  o[0]=s; o[1]=q;
}

__global__ void k_bnstat2(const float* __restrict__ part, const void* __restrict__ g,
                          const void* __restrict__ b, const u32* __restrict__ flag,
                          float2* __restrict__ st)
{
  const int m = (int)flag[0];
  const int c = threadIdx.x;
  float s=0.f,q=0.f;
  for (int w=0;w<256;w++){ s += part[((long)w*256+c)*2]; q += part[((long)w*256+c)*2+1]; }
  const float mean = s*(1.f/32768.f);
  float v = q*(1.f/32768.f) - mean*mean;
  v = fmaxf(v, 0.f);
  const float sc = ldv(g,c,m) / sqrtf(v + 1e-5f);
  st[c] = make_float2(sc, ldv(b,c,m) - mean*sc);
}

// ---------------- weight prepacks (mode-aware loads) ----------------
__global__ void k_prep_w1(const void* a,const void* b,const void* c,const void* d,
                          const void* ba,const void* bb,const void* bc,const void* bd,
                          const u32* flag, u16* w1p, u16* bp1)
{
  const int m = (int)flag[0];
  const int idx = blockIdx.x*256 + threadIdx.x;     // 294912 = 4*128*9*64
  if (idx < 294912){
    const int ci = idx & 63, r = (idx>>6)%9, co = (idx/576)%128, brn = idx/73728;
    const void* w = brn==0?a:brn==1?b:brn==2?c:d;
    u16 v = 0;
    if (ci < 35) v = f2b(ldv(w, ((long)co*35 + ci)*9 + r, m));
    w1p[idx] = v;
  }
  if (idx < 512){
    const int brn = idx>>7, co = idx&127;
    const void* bb2 = brn==0?ba:brn==1?bb:brn==2?bc:bd;
    bp1[idx] = f2b(ldv(bb2, co, m));
  }
}

// gw weights: [co''][ci][tap] -> [co''][tap][ci]; co'' = c*9+k (native order)
__global__ void k_prep_gw(const void* __restrict__ w2, const void* __restrict__ b2,
                          const u32* __restrict__ flag,
                          u16* __restrict__ w2p, u16* __restrict__ bp)
{
  const int m = (int)flag[0];
  const long idx = (long)blockIdx.x*256 + threadIdx.x;   // 2654208 = 2304*9*128
  if (idx < 2654208L){
    const int ci  = (int)(idx & 127);
    const int tap = (int)((idx>>7)%9);
    const int co  = (int)(idx/1152);
    w2p[idx] = f2b(ldv(w2, ((long)co*128 + ci)*9 + tap, m));
  }
  if (idx < 2304) bp[idx] = f2b(ldv(b2, idx, m));
}

__global__ void k_prep_se(const void* wa, const void* wb, const void* ba, const void* bb,
                          const u32* flag, u16* w2p, u16* bp)
{
  const int m = (int)flag[0];
  const int idx = blockIdx.x*256 + threadIdx.x;     // 589824 = 2*256*9*128
  if (idx < 589824){
    const int ci = idx & 127, r = (idx>>7)%9, co = (idx/1152)%256, brn = idx/294912;
    const void* w = brn ? wb : wa;
    w2p[idx] = f2b(ldv(w, ((long)co*128 + ci)*9 + r, m));
  }
  if (idx < 512){
    const int brn = idx>>8, co = idx&255;
    bp[idx] = f2b(ldv(brn?bb:ba, co, m));
  }
}

__global__ void k_prep_c(const void* c1w, const void* c1b, const void* c3w, const void* c3b,
                         const u32* flag, u16* c1wp, u16* c1bp, u16* c3wp, u16* c3bp)
{
  const int m = (int)flag[0];
  const int idx = blockIdx.x*256 + threadIdx.x;     // 65536
  if (idx < 65536){
    c1wp[idx] = f2b(ldv(c1w, idx, m));
    c3wp[idx] = f2b(ldv(c3w, idx, m));
  }
  if (idx < 256){
    c1bp[idx] = f2b(ldv(c1b, idx, m));
    c3bp[idx] = f2b(ldv(c3b, idx, m));
  }
}

// ---------------- input transposes (mode-aware) ----------------
__global__ __launch_bounds__(256)
void k_seg_t(const void* __restrict__ seg, const u32* __restrict__ flag,
             u16* __restrict__ segt)
{
  __shared__ u16 lt[8192];     // [x 128][ci 64]
  const int m = (int)flag[0];
  const int y = blockIdx.x, n = blockIdx.y, t = threadIdx.x;
  for (int i=t;i<8192;i+=256) lt[i]=0;
  __syncthreads();
  for (int idx=t; idx<128*35; idx+=256){
    const int x = idx/35, ci = idx - x*35;
    lt[x*64+ci] = f2b(ldv(seg, (((long)n*35 + ci)*256 + 2*y)*256 + 2*x, m));
  }
  __syncthreads();
  const int x = t>>1, hf = t&1;
  u16* o = segt + (((long)n*PH + (y+1))*PH + (x+1))*64 + hf*32;
  #pragma unroll
  for (int i=0;i<4;i++) *(int4*)(o + i*8) = *(const int4*)&lt[x*64 + hf*32 + i*8];
}

// x NCHW -> padded NHWC; grid (128 y, 2 n, 4 cb), vectorized
__global__ __launch_bounds__(256)
void k_x_t(const void* __restrict__ x, const u32* __restrict__ flag,
           u16* __restrict__ xt)
{
  __shared__ u16 lt[128*72];
  const int m = (int)flag[0];
  const int y = blockIdx.x, n = blockIdx.y, cb = blockIdx.z;
  const int t = threadIdx.x;
  const long base = ((long)n*256 + cb*64)*PX + (long)y*W_;
  if (m){
    const float* xf = (const float*)x + base;
    #pragma unroll
    for (int i=0;i<8;i++){
      const int q = i*256 + t;          // 2048 float4
      const int c = q>>5, x4 = (q&31)*4;
      const float4 v = *(const float4*)(xf + (long)c*PX + x4);
      lt[(x4+0)*72 + c] = f2b(v.x);
      lt[(x4+1)*72 + c] = f2b(v.y);
      lt[(x4+2)*72 + c] = f2b(v.z);
      lt[(x4+3)*72 + c] = f2b(v.w);
    }
  } else {
    const u16* xu = (const u16*)x + base;
    #pragma unroll
    for (int i=0;i<4;i++){
      const int q = i*256 + t;          // 1024 ushort8
      const int c = q>>4, x8 = (q&15)*8;
      const bf16x8 v = *(const bf16x8*)(xu + (long)c*PX + x8);
      #pragma unroll
      for (int e=0;e<8;e++) lt[(x8+e)*72 + c] = (u16)v[e];
    }
  }
  __syncthreads();
  const int xx = t>>1, hf = t&1;
  u16* o = xt + (((long)n*PH + (y+1))*PH + (xx+1))*256 + cb*64 + hf*32;
  #pragma unroll
  for (int i=0;i<4;i++) *(int4*)(o+i*8) = *(const int4*)&lt[xx*72 + hf*32 + i*8];
}

extern "C" void kernel_launch(void* const* d_in, const int* in_sizes, int n_in,
                              void* d_out, int out_size, void* d_ws, size_t ws_size,
                              hipStream_t stream)
{
  (void)in_sizes; (void)n_in; (void)out_size; (void)ws_size;
  const void* x      = d_in[0];
  const void* seg    = d_in[1];
  const void* gw1_w1 = d_in[2];
  const void* gw1_b1 = d_in[3];
  const void* gw1_w2 = d_in[4];
  const void* gw1_b2 = d_in[5];
  const void* gw2_w1 = d_in[6];
  const void* gw2_b1 = d_in[7];
  const void* gw2_w2 = d_in[8];
  const void* gw2_b2 = d_in[9];
  const void* se1_w1 = d_in[10];
  const void* se1_b1 = d_in[11];
  const void* se1_w2 = d_in[12];
  const void* se1_b2 = d_in[13];
  const void* se2_w1 = d_in[14];
  const void* se2_b1 = d_in[15];
  const void* se2_w2 = d_in[16];
  const void* se2_b2 = d_in[17];
  const void* c1w = d_in[18];
  const void* c1b = d_in[19];
  const void* c3w = d_in[20];
  const void* c3b = d_in[21];
  const void* bn1g = d_in[22];
  const void* bn1b = d_in[23];
  const void* bn2g = d_in[24];
  const void* bn2b = d_in[25];
  u16* ws = (u16*)d_ws;

  // workspace layout (u16 element offsets), peak = 59,882,112 u16 = 119.8 MB
  u16* segt  = ws;                       // 2,163,200
  u16* xt    = ws + 2163200L;            // 8,652,800  (= t1, serialized overlay)
  u16* t1    = xt;
  u16* dd    = ws + 10816000L;           // 8,388,608
  u16* sw1   = ws + 19204608L;           // 8,388,608
  u16* sw2   = ws + 27593216L;           // 8,388,608
  u16* w1p   = ws + 35981824L;           // 294,912
  u16* bp1   = ws + 36276736L;           // 512
  u16* w2pg1 = ws + 36277248L;           // 2,654,208
  u16* w2pg2 = ws + 38931456L;           // 2,654,208
  u16* bpg   = ws + 41585664L;           // 4,608
  u16* w2ps  = ws + 41590272L;           // 589,824
  u16* bps   = ws + 42180096L;           // 512
  u16* c1wp  = ws + 42180608L;           // 65,536
  u16* c1bp  = ws + 42246144L;           // 256
  u16* c3wp  = ws + 42246400L;           // 65,536
  u16* c3bp  = ws + 42311936L;           // 256
  float*  part = (float*)(ws + 42312192L);   // 131,072 f32 (262,144 u16)
  float2* st1  = (float2*)(ws + 42574336L);  // 256 float2 (1,024 u16)
  float2* st2  = (float2*)(ws + 42575360L);  // 256 float2 (1,024 u16)
  u32*    flag = (u32*)(ws + 42576384L);     // 1 u32 (+pad)
  u16* h1t   = ws + 42576512L;           // 17,305,600 [4 branches x 2*130*130*128]

  // zero pads: segt memset (small) + h1t border-only kernel
  hipMemsetAsync(segt, 0, 4326400ULL, stream);
  k_zpad<<<dim3(8),256,0,stream>>>(h1t);

  // dtype autodetect, then prepacks + transposes
  k_detect<<<dim3(1),256,0,stream>>>((const u32*)x, flag);
  k_prep_w1<<<dim3(1152),256,0,stream>>>(gw1_w1,gw2_w1,se1_w1,se2_w1,
                                         gw1_b1,gw2_b1,se1_b1,se2_b1, flag, w1p, bp1);
  k_prep_gw<<<dim3(10368),256,0,stream>>>(gw1_w2, gw1_b2, flag, w2pg1, bpg);
  k_prep_gw<<<dim3(10368),256,0,stream>>>(gw2_w2, gw2_b2, flag, w2pg2, bpg+2304);
  k_prep_se<<<dim3(2304),256,0,stream>>>(se1_w2, se2_w2, se1_b2, se2_b2, flag, w2ps, bps);
  k_prep_c<<<dim3(256),256,0,stream>>>(c1w, c1b, c3w, c3b, flag, c1wp, c1bp, c3wp, c3bp);
  k_seg_t<<<dim3(128,2),256,0,stream>>>(seg, flag, segt);
  k_x_t<<<dim3(128,2,4),256,0,stream>>>(x, flag, xt);

  // branch conv1 (4 branches, relu) : segmap -> h1t[br]
  k_convgemm<64,9,1><<<dim3(128,4,2),256,0,stream>>>(
      segt, w1p, bp1, nullptr, h1t, 1,
      0L, 73728L, 128, 4326400L,
      1081600L, 8320, 8384,
      2163200L, 16640L, 128, 16768, 0L, 0,
      nullptr, nullptr, nullptr);

  // se conv2 (2 branches, sigmoid) : h1t[2],h1t[3] -> sw1, sw2
  k_convgemm<128,9,2><<<dim3(128,4,2),256,0,stream>>>(
      h1t + 2*4326400L, w2ps, bps, nullptr, sw1, 2,
      4326400L, 294912L, 256, 8388608L,
      2163200L, 16640, 16768,
      4194304L, 32768L, 256, 0, 0L, 0,
      nullptr, nullptr, nullptr);

  // BN1 stats from xt
  k_bnstat1<<<dim3(256),256,0,stream>>>(xt, part);
  k_bnstat2<<<dim3(1),256,0,stream>>>(part, bn1g, bn1b, flag, st1);

  // fused gw conv + BN1 + depthwise, branch 1: h1t[0] x xt -> dd
  k_convdw<<<dim3(128,16,2),256,0,stream>>>(h1t, w2pg1, bpg, xt, st1, dd);

  // 1x1 conv #1 (+bias, *sw1, lrelu) -> t1 (padded, overlays xt)
  k_convgemm<256,1,3><<<dim3(128,2,2),256,0,stream>>>(
      dd, c1wp, c1bp, sw1, t1, 2,
      0L, 0L, 0, 0L,
      4194304L, 32768, 0,
      4326400L, 33280L, 256, 33536, 4194304L, 32768,
      nullptr, nullptr, nullptr);

  // BN2 stats from t1
  k_bnstat1<<<dim3(256),256,0,stream>>>(t1, part);
  k_bnstat2<<<dim3(1),256,0,stream>>>(part, bn2g, bn2b, flag, st2);

  // fused gw conv + BN2 + depthwise, branch 2: h1t[1] x t1 -> dd
  k_convdw<<<dim3(128,16,2),256,0,stream>>>(h1t + 4326400L, w2pg2, bpg+2304, t1, st2, dd);

  // 1x1 conv #2 (+bias, *sw2, lrelu) + fused residual add -> d_out (NCHW)
  k_convgemm<256,1,4><<<dim3(128,2,2),256,0,stream>>>(
      dd, c3wp, c3bp, sw2, dd, 2,
      0L, 0L, 0, 0L,
      4194304L, 32768, 0,
      0L, 0L, 256, 0, 4194304L, 32768,
      x, flag, d_out);
}

// Round 13
// 680.424 us; speedup vs baseline: 1.1702x; 1.1702x over previous
//
#include <hip/hip_runtime.h>
#include <hip/hip_bf16.h>

typedef unsigned short u16;
typedef unsigned int u32;
typedef __attribute__((ext_vector_type(8))) short bf16x8;
typedef __attribute__((ext_vector_type(4))) float f32x4;
typedef __attribute__((address_space(3))) u32 lds_u32;
typedef const __attribute__((address_space(1))) u32 glb_u32;

#define H_ 128
#define W_ 128
#define PX 16384
#define PH 130

__device__ __forceinline__ float b2f(u16 h){ u32 u = ((u32)h)<<16; return __uint_as_float(u); }
__device__ __forceinline__ u16 f2b(float f){
  u32 u = __float_as_uint(f);
  u32 r = (u + 0x7fffu + ((u>>16)&1u)) >> 16;
  return (u16)r;
}
// mode: 1 = inputs are float32, 0 = inputs are bf16
__device__ __forceinline__ float ldv(const void* p, long i, int m){
  return m ? ((const float*)p)[i] : b2f(((const u16*)p)[i]);
}
__device__ __forceinline__ void gload16(const u16* g, u16* l){
  __builtin_amdgcn_global_load_lds((glb_u32*)g, (lds_u32*)l, 16, 0, 0);
}

// ---------------- dtype autodetect ----------------
__global__ void k_detect(const u32* __restrict__ xw, u32* __restrict__ flag){
  __shared__ int cnt[256];
  const int t = threadIdx.x;
  int c = 0;
  #pragma unroll
  for (int i=0;i<4;i++){
    const u32 w = xw[t*4+i];
    const u32 e = ((w & 0xFFFFu) >> 7) & 0xFF;
    if (e >= 90 && e <= 140) c++;     // bf16 low-half exponent range for N(0,1)
  }
  cnt[t] = c; __syncthreads();
  for (int s=128;s>0;s>>=1){ if (t<s) cnt[t]+=cnt[t+s]; __syncthreads(); }
  if (t==0) flag[0] = (cnt[0] < 512) ? 1u : 0u;   // few hits -> f32 data
}

// ---------------- border-zero for h1t pads (replaces 34.6MB memset) ----------------
__global__ void k_zpad(u16* __restrict__ h1t){
  const int p = blockIdx.x;            // 8 planes: br = p>>1, n = p&1
  u16* base = h1t + (long)p*2163200L;  // [130][130][128]
  const int t = threadIdx.x;
  const int4 z = make_int4(0,0,0,0);
  for (int idx=t; idx<8256; idx+=256){
    long off;
    if (idx < 2080)       off = (long)idx*8;                                   // row 0
    else if (idx < 4160)  off = 2146560L + (long)(idx-2080)*8;                 // row 129
    else if (idx < 6208){ const int r = 1 + (idx-4160)/16, w = (idx-4160)%16;  // col 0
                          off = (long)r*16640 + w*8; }
    else {                const int r = 1 + (idx-6208)/16, w = (idx-6208)%16;  // col 129
                          off = (long)r*16640 + 16512 + w*8; }
    *(int4*)(base + off) = z;
  }
}

// ---------------- implicit-GEMM conv kernel (conv1 / se / 1x1) ----------------
// EPI: 0=bias, 1=bias+relu, 2=bias+sigmoid, 3=(bias)*sw+lrelu ->NHWC (+BN partial sums),
//      4=EPI3 math then fused residual add + NCHW write to outF
template<int CIN, int NTAPS, int EPI>
__global__ __launch_bounds__(256, 2)
void k_convgemm(const u16* __restrict__ inp, const u16* __restrict__ wp,
                const u16* __restrict__ bias, const u16* __restrict__ swp,
                u16* __restrict__ outp, int nbco,
                long in_br, long w_br, int bias_br, long out_br,
                long in_n, int in_row, int in_x0,
                long out_n, long out_y, int out_px, int out_x0,
                long sw_n, int sw_y,
                const void* __restrict__ xres, const u32* __restrict__ flagp,
                void* __restrict__ outF, float* __restrict__ partp)
{
  __shared__ u16 ls[17408];          // A:[0,8192) B:[8192,16384); epilogue tile [128][136]
  u16* lsA = ls;
  u16* lsB = ls + 8192;

  const int bx  = blockIdx.x;
  // XCD-aware y swizzle for the 3x3 convs (halo reuse in per-XCD L2); grid.x==128
  const int y   = (NTAPS==9) ? (((bx&7)<<4) | (bx>>3)) : bx;
  const int br  = blockIdx.y / nbco;
  const int cb  = blockIdx.y - br*nbco;
  const int n   = blockIdx.z;
  const int tid = threadIdx.x;
  const int wave = tid >> 6, lane = tid & 63;
  const int l16 = lane & 15, lg = lane >> 4;
  const int chw = (wave >> 1) * 64;   // co half
  const int phw = (wave & 1) * 64;    // px half

  const u16* inb   = inp + (long)br*in_br + (long)n*in_n + in_x0 + (long)y*in_row;
  const u16* wb    = wp  + (long)br*w_br + (long)cb*128*(NTAPS*CIN);
  const u16* biasb = bias + (long)br*bias_br + cb*128;
  u16* outb = outp + (long)br*out_br + (long)n*out_n + out_x0 + (long)y*out_y;

  f32x4 acc[4][4];
  #pragma unroll
  for (int m=0;m<4;m++)
    #pragma unroll
    for (int q=0;q<4;q++) acc[m][q] = (f32x4){0.f,0.f,0.f,0.f};

  const int NSTEP = NTAPS*(CIN/64);
  for (int step=0; step<NSTEP; ++step){
    const int tap = step/(CIN/64);
    const int k0  = (step - tap*(CIN/64))*64;
    const int dy = (NTAPS==1)?0:(tap/3-1);
    const int dx = (NTAPS==1)?0:(tap%3-1);
    const u16* wsrc = wb  + tap*CIN + k0;
    const u16* bsrc = inb + (long)dy*in_row + dx*CIN + k0;
    #pragma unroll
    for (int i=0;i<4;i++){
      const int idx = (wave*4+i)*64 + lane;
      const int r = idx>>3, c = idx&7;
      const int cc = c ^ (r&7);
      gload16(wsrc + (long)r*(NTAPS*CIN) + cc*8, lsA + (wave*4+i)*512);
    }
    #pragma unroll
    for (int i=0;i<4;i++){
      const int idx = (wave*4+i)*64 + lane;
      const int r = idx>>3, c = idx&7;
      const int cc = c ^ (r&7);
      gload16(bsrc + (long)r*CIN + cc*8, lsB + (wave*4+i)*512);
    }
    __syncthreads();
    #pragma unroll
    for (int kk=0;kk<2;kk++){
      bf16x8 af[4], bfr[4];
      const int kc = kk*4 + lg;
      #pragma unroll
      for (int m=0;m<4;m++){
        const int r = chw + m*16 + l16;
        af[m] = *(const bf16x8*)(lsA + r*64 + ((kc ^ (r&7))<<3));
      }
      #pragma unroll
      for (int q=0;q<4;q++){
        const int r = phw + q*16 + l16;
        bfr[q] = *(const bf16x8*)(lsB + r*64 + ((kc ^ (r&7))<<3));
      }
      #pragma unroll
      for (int m=0;m<4;m++)
        #pragma unroll
        for (int q=0;q<4;q++)
          acc[m][q] = __builtin_amdgcn_mfma_f32_16x16x32_bf16(af[m], bfr[q], acc[m][q], 0,0,0);
    }
    __syncthreads();
  }

  // epilogue: acc -> LDS tile [px 128][co 136]
  #pragma unroll
  for (int m=0;m<4;m++){
    const int co = chw + m*16 + lg*4;
    const ushort4 bb = *(const ushort4*)(biasb + co);
    const float bv0=b2f(bb.x), bv1=b2f(bb.y), bv2=b2f(bb.z), bv3=b2f(bb.w);
    #pragma unroll
    for (int q=0;q<4;q++){
      const int px = phw + q*16 + l16;
      float v0 = acc[m][q][0] + bv0;
      float v1 = acc[m][q][1] + bv1;
      float v2 = acc[m][q][2] + bv2;
      float v3 = acc[m][q][3] + bv3;
      if (EPI==1){
        v0=fmaxf(v0,0.f); v1=fmaxf(v1,0.f); v2=fmaxf(v2,0.f); v3=fmaxf(v3,0.f);
      } else if (EPI==2){
        v0 = 1.f/(1.f+__expf(-v0)); v1 = 1.f/(1.f+__expf(-v1));
        v2 = 1.f/(1.f+__expf(-v2)); v3 = 1.f/(1.f+__expf(-v3));
      } else if (EPI==3 || EPI==4){
        const ushort4 sv = *(const ushort4*)(swp + (long)n*sw_n + (long)y*sw_y + (long)px*256 + cb*128 + co);
        v0 *= b2f(sv.x); v1 *= b2f(sv.y); v2 *= b2f(sv.z); v3 *= b2f(sv.w);
        v0 = v0>=0.f? v0 : 0.2f*v0;  v1 = v1>=0.f? v1 : 0.2f*v1;
        v2 = v2>=0.f? v2 : 0.2f*v2;  v3 = v3>=0.f? v3 : 0.2f*v3;
      }
      ushort4 ov; ov.x=f2b(v0); ov.y=f2b(v1); ov.z=f2b(v2); ov.w=f2b(v3);
      *(ushort4*)(ls + px*136 + co) = ov;
    }
  }
  __syncthreads();
  if (EPI == 4){
    // fused: out[n][c][y][:] = x + dx3, NCHW, coalesced per co row
    const int m2 = (int)flagp[0];
    const int co = tid>>1, hf2 = tid&1;
    const long xoff = (((long)n*256 + cb*128 + co)*H_ + y)*W_ + hf2*64;
    const u16* lrow = ls + (hf2*64)*136 + co;
    if (m2){
      const float* xf = (const float*)xres;
      float* of = (float*)outF;
      #pragma unroll
      for (int i=0;i<16;i++){
        const float4 xv = *(const float4*)(xf + xoff + i*4);
        float4 ov;
        ov.x = xv.x + b2f(lrow[(i*4+0)*136]);
        ov.y = xv.y + b2f(lrow[(i*4+1)*136]);
        ov.z = xv.z + b2f(lrow[(i*4+2)*136]);
        ov.w = xv.w + b2f(lrow[(i*4+3)*136]);
        *(float4*)(of + xoff + i*4) = ov;
      }
    } else {
      const u16* xu = (const u16*)xres;
      u16* ou = (u16*)outF;
      #pragma unroll
      for (int i=0;i<8;i++){
        const bf16x8 xv = *(const bf16x8*)(xu + xoff + i*8);
        bf16x8 ov;
        #pragma unroll
        for (int e=0;e<8;e++)
          ov[e] = (short)f2b(b2f((u16)xv[e]) + b2f(lrow[(i*8+e)*136]));
        *(bf16x8*)(ou + xoff + i*8) = ov;
      }
    }
  } else {
    const int row = tid>>1, hf = tid&1;
    u16* og = outb + (long)row*out_px + cb*128 + hf*64;
    #pragma unroll
    for (int i=0;i<8;i++)
      *(int4*)(og + i*8) = *(const int4*)(ls + row*136 + hf*64 + i*8);
    if (EPI == 3){
      // fused BN2 partial sums over this block's 128px x 128co tile
      if (tid < 128){
        const int co = tid;
        float s = 0.f, q = 0.f;
        for (int px=0; px<128; ++px){
          const float v = b2f(ls[px*136 + co]);
          s += v; q += v*v;
        }
        float* o = partp + (((long)n*128 + y)*256 + cb*128 + co)*2;
        o[0] = s; o[1] = q;
      }
    }
  }
}

// ---------------- FUSED gw-conv + BN-affine + dynamic depthwise (v6, r11-proven) ----------------
__global__ __launch_bounds__(256, 2)
void k_convdw(const u16* __restrict__ h1,      // padded [n][130][130][128]
              const u16* __restrict__ wp,      // [2304][9][128]
              const u16* __restrict__ bp,      // [2304] (co''=c*9+k order)
              const u16* __restrict__ xh,      // padded [n][130][130][256] (pre-BN act)
              const float2* __restrict__ ss,   // BN (scale, shift)
              u16* __restrict__ dd)            // [n][16384][256]
{
  __shared__ u16 ls[19008];   // 38,016 B; staging A[0,9216) B[9216,17408); ct[144][132] overlays
  u16* lsA = ls;
  u16* lsB = ls + 9216;

  const int bx = blockIdx.x, mt = blockIdx.y, n = blockIdx.z;   // mt in [0,16)
  const int y = ((bx&7)<<4) | (bx>>3);      // XCD-band swizzle (bijective, 128%8==0)
  const int tid = threadIdx.x;
  const int wave = tid >> 6, lane = tid & 63;
  const int l16 = lane & 15, lg = lane >> 4;
  const int wn = wave * 32;           // px offset of wave

  const u16* wb = wp + (long)mt*144*1152;

  f32x4 acc[9][2];
  #pragma unroll
  for (int m=0;m<9;m++){ acc[m][0]=(f32x4){0,0,0,0}; acc[m][1]=(f32x4){0,0,0,0}; }

  for (int s=0; s<18; ++s){
    const int tap = s >> 1;
    const int k0  = (s & 1) * 64;
    const int dy = tap/3 - 1, dx = tap%3 - 1;
    const u16* wsrc = wb + tap*128 + k0;
    const u16* bsrc = h1 + (((long)n*PH + (y+dy+1))*PH + (dx+1))*128 + k0;
    // stage A: 144 rows x 64 ci = 1152 chunks (4 x 256 + 128)
    #pragma unroll
    for (int i=0;i<4;i++){
      const int g = i*256 + tid;
      const int r = g>>3, c = g&7, sp = c ^ (r&7);
      gload16(wsrc + (long)r*1152 + sp*8, lsA + g*8);
    }
    if (tid < 128){
      const int g = 1024 + tid;
      const int r = g>>3, c = g&7, sp = c ^ (r&7);
      gload16(wsrc + (long)r*1152 + sp*8, lsA + g*8);
    }
    // stage B: 128 px x 64 ci = 1024 chunks (4 x 256)
    #pragma unroll
    for (int i=0;i<4;i++){
      const int g = i*256 + tid;
      const int p = g>>3, c = g&7, sp = c ^ (p&7);
      gload16(bsrc + (long)p*128 + sp*8, lsB + g*8);
    }
    __syncthreads();
    #pragma unroll
    for (int kk=0;kk<2;kk++){
      const int kc = kk*4 + lg;
      bf16x8 bfr[2];
      #pragma unroll
      for (int q=0;q<2;q++){
        const int rb = wn + q*16 + l16;
        bfr[q] = *(const bf16x8*)(lsB + rb*64 + ((kc ^ (rb&7))<<3));
      }
      #pragma unroll
      for (int m=0;m<9;m++){
        const int ra = m*16 + l16;
        const bf16x8 a = *(const bf16x8*)(lsA + ra*64 + ((kc ^ (ra&7))<<3));
        acc[m][0] = __builtin_amdgcn_mfma_f32_16x16x32_bf16(a, bfr[0], acc[m][0], 0,0,0);
        acc[m][1] = __builtin_amdgcn_mfma_f32_16x16x32_bf16(a, bfr[1], acc[m][1], 0,0,0);
      }
    }
    __syncthreads();
  }

  // ---- epilogue 1: cw + bias -> ct[144][132] (all 4 waves, disjoint px) ----
  u16* ct = ls;
  #pragma unroll
  for (int m=0;m<9;m++){
    const int r0 = m*16 + lg*4;
    const ushort4 bb = *(const ushort4*)(bp + mt*144 + r0);
    const float bv0=b2f(bb.x), bv1=b2f(bb.y), bv2=b2f(bb.z), bv3=b2f(bb.w);
    #pragma unroll
    for (int q=0;q<2;q++){
      const int px = wn + q*16 + l16;
      ct[(r0+0)*132 + px] = f2b(acc[m][q][0] + bv0);
      ct[(r0+1)*132 + px] = f2b(acc[m][q][1] + bv1);
      ct[(r0+2)*132 + px] = f2b(acc[m][q][2] + bv2);
      ct[(r0+3)*132 + px] = f2b(acc[m][q][3] + bv3);
    }
  }
  __syncthreads();

  // ---- epilogue 2: depthwise. 256 threads: cl = tid&15 channel, xg = tid>>4 ----
  const int cl = tid & 15;
  const int c  = mt*16 + cl;
  const float2 sc = ss[c];
  const int xg = tid >> 4;
  #pragma unroll
  for (int i=0;i<8;i++){
    const int x = i*16 + xg;
    float a = 0.f;
    #pragma unroll
    for (int k=0;k<9;k++){
      const int ddy = k/3-1, ddx = k%3-1;
      const int gy = y+ddy, gx = x+ddx;
      if ((unsigned)gy < 128u && (unsigned)gx < 128u){
        const float xv = b2f(xh[(((long)n*PH + (gy+1))*PH + (gx+1))*256 + c]);
        const float w  = b2f(ct[(cl*9+k)*132 + x]);
        a += (xv*sc.x + sc.y) * w;
      }
    }
    dd[(((long)n*PX) + (long)y*W_ + x)*256 + c] = f2b(a);
  }
}

// ---------------- BN stage 2 (stage 1 is fused into producers) ----------------
__global__ void k_bnstat2(const float* __restrict__ part, const void* __restrict__ g,
                          const void* __restrict__ b, const u32* __restrict__ flag,
                          float2* __restrict__ st)
{
  const int m = (int)flag[0];
  const int c = threadIdx.x;
  float s=0.f,q=0.f;
  for (int w=0;w<256;w++){ s += part[((long)w*256+c)*2]; q += part[((long)w*256+c)*2+1]; }
  const float mean = s*(1.f/32768.f);
  float v = q*(1.f/32768.f) - mean*mean;
  v = fmaxf(v, 0.f);
  const float sc = ldv(g,c,m) / sqrtf(v + 1e-5f);
  st[c] = make_float2(sc, ldv(b,c,m) - mean*sc);
}

// ---------------- weight prepacks (mode-aware loads) ----------------
__global__ void k_prep_w1(const void* a,const void* b,const void* c,const void* d,
                          const void* ba,const void* bb,const void* bc,const void* bd,
                          const u32* flag, u16* w1p, u16* bp1)
{
  const int m = (int)flag[0];
  const int idx = blockIdx.x*256 + threadIdx.x;     // 294912 = 4*128*9*64
  if (idx < 294912){
    const int ci = idx & 63, r = (idx>>6)%9, co = (idx/576)%128, brn = idx/73728;
    const void* w = brn==0?a:brn==1?b:brn==2?c:d;
    u16 v = 0;
    if (ci < 35) v = f2b(ldv(w, ((long)co*35 + ci)*9 + r, m));
    w1p[idx] = v;
  }
  if (idx < 512){
    const int brn = idx>>7, co = idx&127;
    const void* bb2 = brn==0?ba:brn==1?bb:brn==2?bc:bd;
    bp1[idx] = f2b(ldv(bb2, co, m));
  }
}

// gw weights: native [co''][ci 128][tap 9] -> [co''][tap][ci], COALESCED via LDS.
// block b handles co'' = 2b, 2b+1 (2304 elements). Also bias in blocks 0..8.
__global__ void k_prep_gw(const void* __restrict__ w2, const void* __restrict__ b2,
                          const u32* __restrict__ flag,
                          u16* __restrict__ w2p, u16* __restrict__ bp)
{
  __shared__ u16 lt[2304];
  const int m = (int)flag[0];
  const int b = blockIdx.x;            // [0,1152)
  const int t = threadIdx.x;
  #pragma unroll
  for (int i=0;i<9;i++){
    const int g = i*256 + t;           // [0,2304)
    const long src = (long)b*2304 + g; // flat native order (coalesced read)
    const int lco = g/1152, rem = g - lco*1152;
    const int ci = rem/9, tap = rem - ci*9;
    lt[lco*1152 + tap*128 + ci] = f2b(ldv(w2, src, m));
  }
  __syncthreads();
  #pragma unroll
  for (int i=0;i<9;i++){
    const int g = i*256 + t;
    w2p[(long)b*2304 + g] = lt[g];     // coalesced write in target order
  }
  if (b < 9){
    const int bi = b*256 + t;
    if (bi < 2304) bp[bi] = f2b(ldv(b2, bi, m));
  }
}

__global__ void k_prep_se(const void* wa, const void* wb, const void* ba, const void* bb,
                          const u32* flag, u16* w2p, u16* bp)
{
  const int m = (int)flag[0];
  const int idx = blockIdx.x*256 + threadIdx.x;     // 589824 = 2*256*9*128
  if (idx < 589824){
    const int ci = idx & 127, r = (idx>>7)%9, co = (idx/1152)%256, brn = idx/294912;
    const void* w = brn ? wb : wa;
    w2p[idx] = f2b(ldv(w, ((long)co*128 + ci)*9 + r, m));
  }
  if (idx < 512){
    const int brn = idx>>8, co = idx&255;
    bp[idx] = f2b(ldv(brn?bb:ba, co, m));
  }
}

__global__ void k_prep_c(const void* c1w, const void* c1b, const void* c3w, const void* c3b,
                         const u32* flag, u16* c1wp, u16* c1bp, u16* c3wp, u16* c3bp)
{
  const int m = (int)flag[0];
  const int idx = blockIdx.x*256 + threadIdx.x;     // 65536
  if (idx < 65536){
    c1wp[idx] = f2b(ldv(c1w, idx, m));
    c3wp[idx] = f2b(ldv(c3w, idx, m));
  }
  if (idx < 256){
    c1bp[idx] = f2b(ldv(c1b, idx, m));
    c3bp[idx] = f2b(ldv(c3b, idx, m));
  }
}

// ---------------- input transposes (mode-aware) ----------------
__global__ __launch_bounds__(256)
void k_seg_t(const void* __restrict__ seg, const u32* __restrict__ flag,
             u16* __restrict__ segt)
{
  __shared__ u16 lt[8192];     // [x 128][ci 64]
  const int m = (int)flag[0];
  const int y = blockIdx.x, n = blockIdx.y, t = threadIdx.x;
  for (int i=t;i<8192;i+=256) lt[i]=0;
  __syncthreads();
  for (int idx=t; idx<128*35; idx+=256){
    const int x = idx/35, ci = idx - x*35;
    lt[x*64+ci] = f2b(ldv(seg, (((long)n*35 + ci)*256 + 2*y)*256 + 2*x, m));
  }
  __syncthreads();
  const int x = t>>1, hf = t&1;
  u16* o = segt + (((long)n*PH + (y+1))*PH + (x+1))*64 + hf*32;
  #pragma unroll
  for (int i=0;i<4;i++) *(int4*)(o + i*8) = *(const int4*)&lt[x*64 + hf*32 + i*8];
}

// x NCHW -> padded NHWC + fused BN1 partial sums; grid (128 y, 2 n, 4 cb)
__global__ __launch_bounds__(256)
void k_x_t(const void* __restrict__ x, const u32* __restrict__ flag,
           u16* __restrict__ xt, float* __restrict__ part)
{
  __shared__ u16 lt[128*72];
  const int m = (int)flag[0];
  const int y = blockIdx.x, n = blockIdx.y, cb = blockIdx.z;
  const int t = threadIdx.x;
  const long base = ((long)n*256 + cb*64)*PX + (long)y*W_;
  if (m){
    const float* xf = (const float*)x + base;
    #pragma unroll
    for (int i=0;i<8;i++){
      const int q = i*256 + t;          // 2048 float4
      const int c = q>>5, x4 = (q&31)*4;
      const float4 v = *(const float4*)(xf + (long)c*PX + x4);
      lt[(x4+0)*72 + c] = f2b(v.x);
      lt[(x4+1)*72 + c] = f2b(v.y);
      lt[(x4+2)*72 + c] = f2b(v.z);
      lt[(x4+3)*72 + c] = f2b(v.w);
    }
  } else {
    const u16* xu = (const u16*)x + base;
    #pragma unroll
    for (int i=0;i<4;i++){
      const int q = i*256 + t;          // 1024 ushort8
      const int c = q>>4, x8 = (q&15)*8;
      const bf16x8 v = *(const bf16x8*)(xu + (long)c*PX + x8);
      #pragma unroll
      for (int e=0;e<8;e++) lt[(x8+e)*72 + c] = (u16)v[e];
    }
  }
  __syncthreads();
  const int xx = t>>1, hf = t&1;
  u16* o = xt + (((long)n*PH + (y+1))*PH + (xx+1))*256 + cb*64 + hf*32;
  #pragma unroll
  for (int i=0;i<4;i++) *(int4*)(o+i*8) = *(const int4*)&lt[xx*72 + hf*32 + i*8];
  // fused BN1 partial sums (matches old k_bnstat1 layout exactly)
  if (t < 64){
    float s = 0.f, q = 0.f;
    for (int xi=0; xi<128; ++xi){
      const float v = b2f(lt[xi*72 + t]);
      s += v; q += v*v;
    }
    float* op = part + (((long)n*128 + y)*256 + cb*64 + t)*2;
    op[0] = s; op[1] = q;
  }
}

extern "C" void kernel_launch(void* const* d_in, const int* in_sizes, int n_in,
                              void* d_out, int out_size, void* d_ws, size_t ws_size,
                              hipStream_t stream)
{
  (void)in_sizes; (void)n_in; (void)out_size; (void)ws_size;
  const void* x      = d_in[0];
  const void* seg    = d_in[1];
  const void* gw1_w1 = d_in[2];
  const void* gw1_b1 = d_in[3];
  const void* gw1_w2 = d_in[4];
  const void* gw1_b2 = d_in[5];
  const void* gw2_w1 = d_in[6];
  const void* gw2_b1 = d_in[7];
  const void* gw2_w2 = d_in[8];
  const void* gw2_b2 = d_in[9];
  const void* se1_w1 = d_in[10];
  const void* se1_b1 = d_in[11];
  const void* se1_w2 = d_in[12];
  const void* se1_b2 = d_in[13];
  const void* se2_w1 = d_in[14];
  const void* se2_b1 = d_in[15];
  const void* se2_w2 = d_in[16];
  const void* se2_b2 = d_in[17];
  const void* c1w = d_in[18];
  const void* c1b = d_in[19];
  const void* c3w = d_in[20];
  const void* c3b = d_in[21];
  const void* bn1g = d_in[22];
  const void* bn1b = d_in[23];
  const void* bn2g = d_in[24];
  const void* bn2b = d_in[25];
  u16* ws = (u16*)d_ws;

  // workspace layout (u16 element offsets), peak = 59,882,112 u16 = 119.8 MB
  u16* segt  = ws;                       // 2,163,200
  u16* xt    = ws + 2163200L;            // 8,652,800  (= t1, serialized overlay)
  u16* t1    = xt;
  u16* dd    = ws + 10816000L;           // 8,388,608
  u16* sw1   = ws + 19204608L;           // 8,388,608
  u16* sw2   = ws + 27593216L;           // 8,388,608
  u16* w1p   = ws + 35981824L;           // 294,912
  u16* bp1   = ws + 36276736L;           // 512
  u16* w2pg1 = ws + 36277248L;           // 2,654,208
  u16* w2pg2 = ws + 38931456L;           // 2,654,208
  u16* bpg   = ws + 41585664L;           // 4,608
  u16* w2ps  = ws + 41590272L;           // 589,824
  u16* bps   = ws + 42180096L;           // 512
  u16* c1wp  = ws + 42180608L;           // 65,536
  u16* c1bp  = ws + 42246144L;           // 256
  u16* c3wp  = ws + 42246400L;           // 65,536
  u16* c3bp  = ws + 42311936L;           // 256
  float*  part = (float*)(ws + 42312192L);   // 131,072 f32 (262,144 u16)
  float2* st1  = (float2*)(ws + 42574336L);  // 256 float2 (1,024 u16)
  float2* st2  = (float2*)(ws + 42575360L);  // 256 float2 (1,024 u16)
  u32*    flag = (u32*)(ws + 42576384L);     // 1 u32 (+pad)
  u16* h1t   = ws + 42576512L;           // 17,305,600 [4 branches x 2*130*130*128]

  // zero pads: segt memset (small) + h1t border-only kernel
  hipMemsetAsync(segt, 0, 4326400ULL, stream);
  k_zpad<<<dim3(8),256,0,stream>>>(h1t);

  // dtype autodetect, then prepacks + transposes
  k_detect<<<dim3(1),256,0,stream>>>((const u32*)x, flag);
  k_prep_w1<<<dim3(1152),256,0,stream>>>(gw1_w1,gw2_w1,se1_w1,se2_w1,
                                         gw1_b1,gw2_b1,se1_b1,se2_b1, flag, w1p, bp1);
  k_prep_gw<<<dim3(1152),256,0,stream>>>(gw1_w2, gw1_b2, flag, w2pg1, bpg);
  k_prep_gw<<<dim3(1152),256,0,stream>>>(gw2_w2, gw2_b2, flag, w2pg2, bpg+2304);
  k_prep_se<<<dim3(2304),256,0,stream>>>(se1_w2, se2_w2, se1_b2, se2_b2, flag, w2ps, bps);
  k_prep_c<<<dim3(256),256,0,stream>>>(c1w, c1b, c3w, c3b, flag, c1wp, c1bp, c3wp, c3bp);
  k_seg_t<<<dim3(128,2),256,0,stream>>>(seg, flag, segt);
  k_x_t<<<dim3(128,2,4),256,0,stream>>>(x, flag, xt, part);   // + BN1 partial sums

  // branch conv1 (4 branches, relu) : segmap -> h1t[br]
  k_convgemm<64,9,1><<<dim3(128,4,2),256,0,stream>>>(
      segt, w1p, bp1, nullptr, h1t, 1,
      0L, 73728L, 128, 4326400L,
      1081600L, 8320, 8384,
      2163200L, 16640L, 128, 16768, 0L, 0,
      nullptr, nullptr, nullptr, nullptr);

  // se conv2 (2 branches, sigmoid) : h1t[2],h1t[3] -> sw1, sw2
  k_convgemm<128,9,2><<<dim3(128,4,2),256,0,stream>>>(
      h1t + 2*4326400L, w2ps, bps, nullptr, sw1, 2,
      4326400L, 294912L, 256, 8388608L,
      2163200L, 16640, 16768,
      4194304L, 32768L, 256, 0, 0L, 0,
      nullptr, nullptr, nullptr, nullptr);

  // BN1 stage 2 (stage 1 fused into k_x_t)
  k_bnstat2<<<dim3(1),256,0,stream>>>(part, bn1g, bn1b, flag, st1);

  // fused gw conv + BN1 + depthwise, branch 1: h1t[0] x xt -> dd
  k_convdw<<<dim3(128,16,2),256,0,stream>>>(h1t, w2pg1, bpg, xt, st1, dd);

  // 1x1 conv #1 (+bias, *sw1, lrelu) -> t1 (padded) + BN2 partial sums
  k_convgemm<256,1,3><<<dim3(128,2,2),256,0,stream>>>(
      dd, c1wp, c1bp, sw1, t1, 2,
      0L, 0L, 0, 0L,
      4194304L, 32768, 0,
      4326400L, 33280L, 256, 33536, 4194304L, 32768,
      nullptr, nullptr, nullptr, part);

  // BN2 stage 2
  k_bnstat2<<<dim3(1),256,0,stream>>>(part, bn2g, bn2b, flag, st2);

  // fused gw conv + BN2 + depthwise, branch 2: h1t[1] x t1 -> dd
  k_convdw<<<dim3(128,16,2),256,0,stream>>>(h1t + 4326400L, w2pg2, bpg+2304, t1, st2, dd);

  // 1x1 conv #2 (+bias, *sw2, lrelu) + fused residual add -> d_out (NCHW)
  k_convgemm<256,1,4><<<dim3(128,2,2),256,0,stream>>>(
      dd, c3wp, c3bp, sw2, dd, 2,
      0L, 0L, 0, 0L,
      4194304L, 32768, 0,
      0L, 0L, 256, 0, 4194304L, 32768,
      x, flag, d_out, nullptr);
}

// Round 14
// 596.350 us; speedup vs baseline: 1.3352x; 1.1410x over previous
//
#include <hip/hip_runtime.h>
#include <hip/hip_bf16.h>

typedef unsigned short u16;
typedef unsigned int u32;
typedef __attribute__((ext_vector_type(8))) short bf16x8;
typedef __attribute__((ext_vector_type(4))) float f32x4;
typedef __attribute__((address_space(3))) u32 lds_u32;
typedef const __attribute__((address_space(1))) u32 glb_u32;

#define H_ 128
#define W_ 128
#define PX 16384
#define PH 130

__device__ __forceinline__ float b2f(u16 h){ u32 u = ((u32)h)<<16; return __uint_as_float(u); }
__device__ __forceinline__ u16 f2b(float f){
  u32 u = __float_as_uint(f);
  u32 r = (u + 0x7fffu + ((u>>16)&1u)) >> 16;
  return (u16)r;
}
// mode: 1 = inputs are float32, 0 = inputs are bf16
__device__ __forceinline__ float ldv(const void* p, long i, int m){
  return m ? ((const float*)p)[i] : b2f(((const u16*)p)[i]);
}
__device__ __forceinline__ void gload16(const u16* g, u16* l){
  __builtin_amdgcn_global_load_lds((glb_u32*)g, (lds_u32*)l, 16, 0, 0);
}

// ---------------- dtype autodetect ----------------
__global__ void k_detect(const u32* __restrict__ xw, u32* __restrict__ flag){
  __shared__ int cnt[256];
  const int t = threadIdx.x;
  int c = 0;
  #pragma unroll
  for (int i=0;i<4;i++){
    const u32 w = xw[t*4+i];
    const u32 e = ((w & 0xFFFFu) >> 7) & 0xFF;
    if (e >= 90 && e <= 140) c++;     // bf16 low-half exponent range for N(0,1)
  }
  cnt[t] = c; __syncthreads();
  for (int s=128;s>0;s>>=1){ if (t<s) cnt[t]+=cnt[t+s]; __syncthreads(); }
  if (t==0) flag[0] = (cnt[0] < 512) ? 1u : 0u;   // few hits -> f32 data
}

// ---------------- border-zero for h1t pads (replaces 34.6MB memset) ----------------
__global__ void k_zpad(u16* __restrict__ h1t){
  const int p = blockIdx.x;            // 8 planes: br = p>>1, n = p&1
  u16* base = h1t + (long)p*2163200L;  // [130][130][128]
  const int t = threadIdx.x;
  const int4 z = make_int4(0,0,0,0);
  for (int idx=t; idx<8256; idx+=256){
    long off;
    if (idx < 2080)       off = (long)idx*8;                                   // row 0
    else if (idx < 4160)  off = 2146560L + (long)(idx-2080)*8;                 // row 129
    else if (idx < 6208){ const int r = 1 + (idx-4160)/16, w = (idx-4160)%16;  // col 0
                          off = (long)r*16640 + w*8; }
    else {                const int r = 1 + (idx-6208)/16, w = (idx-6208)%16;  // col 129
                          off = (long)r*16640 + 16512 + w*8; }
    *(int4*)(base + off) = z;
  }
}

// ---------------- implicit-GEMM conv kernel (conv1 / se / 1x1) ----------------
// EPI: 0=bias, 1=bias+relu, 2=bias+sigmoid, 3=(bias)*sw+lrelu ->NHWC (+BN partial sums),
//      4=EPI3 math then fused residual add + NCHW write to outF
template<int CIN, int NTAPS, int EPI>
__global__ __launch_bounds__(256, 2)
void k_convgemm(const u16* __restrict__ inp, const u16* __restrict__ wp,
                const u16* __restrict__ bias, const u16* __restrict__ swp,
                u16* __restrict__ outp, int nbco,
                long in_br, long w_br, int bias_br, long out_br,
                long in_n, int in_row, int in_x0,
                long out_n, long out_y, int out_px, int out_x0,
                long sw_n, int sw_y,
                const void* __restrict__ xres, const u32* __restrict__ flagp,
                void* __restrict__ outF, float* __restrict__ partp)
{
  __shared__ u16 ls[17408];          // A:[0,8192) B:[8192,16384); epilogue tile [128][136]
  u16* lsA = ls;
  u16* lsB = ls + 8192;

  const int bx  = blockIdx.x;
  // XCD-aware y swizzle for the 3x3 convs (halo reuse in per-XCD L2); grid.x==128
  const int y   = (NTAPS==9) ? (((bx&7)<<4) | (bx>>3)) : bx;
  const int br  = blockIdx.y / nbco;
  const int cb  = blockIdx.y - br*nbco;
  const int n   = blockIdx.z;
  const int tid = threadIdx.x;
  const int wave = tid >> 6, lane = tid & 63;
  const int l16 = lane & 15, lg = lane >> 4;
  const int chw = (wave >> 1) * 64;   // co half
  const int phw = (wave & 1) * 64;    // px half

  const u16* inb   = inp + (long)br*in_br + (long)n*in_n + in_x0 + (long)y*in_row;
  const u16* wb    = wp  + (long)br*w_br + (long)cb*128*(NTAPS*CIN);
  const u16* biasb = bias + (long)br*bias_br + cb*128;
  u16* outb = outp + (long)br*out_br + (long)n*out_n + out_x0 + (long)y*out_y;

  f32x4 acc[4][4];
  #pragma unroll
  for (int m=0;m<4;m++)
    #pragma unroll
    for (int q=0;q<4;q++) acc[m][q] = (f32x4){0.f,0.f,0.f,0.f};

  const int NSTEP = NTAPS*(CIN/64);
  for (int step=0; step<NSTEP; ++step){
    const int tap = step/(CIN/64);
    const int k0  = (step - tap*(CIN/64))*64;
    const int dy = (NTAPS==1)?0:(tap/3-1);
    const int dx = (NTAPS==1)?0:(tap%3-1);
    const u16* wsrc = wb  + tap*CIN + k0;
    const u16* bsrc = inb + (long)dy*in_row + dx*CIN + k0;
    #pragma unroll
    for (int i=0;i<4;i++){
      const int idx = (wave*4+i)*64 + lane;
      const int r = idx>>3, c = idx&7;
      const int cc = c ^ (r&7);
      gload16(wsrc + (long)r*(NTAPS*CIN) + cc*8, lsA + (wave*4+i)*512);
    }
    #pragma unroll
    for (int i=0;i<4;i++){
      const int idx = (wave*4+i)*64 + lane;
      const int r = idx>>3, c = idx&7;
      const int cc = c ^ (r&7);
      gload16(bsrc + (long)r*CIN + cc*8, lsB + (wave*4+i)*512);
    }
    __syncthreads();
    #pragma unroll
    for (int kk=0;kk<2;kk++){
      bf16x8 af[4], bfr[4];
      const int kc = kk*4 + lg;
      #pragma unroll
      for (int m=0;m<4;m++){
        const int r = chw + m*16 + l16;
        af[m] = *(const bf16x8*)(lsA + r*64 + ((kc ^ (r&7))<<3));
      }
      #pragma unroll
      for (int q=0;q<4;q++){
        const int r = phw + q*16 + l16;
        bfr[q] = *(const bf16x8*)(lsB + r*64 + ((kc ^ (r&7))<<3));
      }
      #pragma unroll
      for (int m=0;m<4;m++)
        #pragma unroll
        for (int q=0;q<4;q++)
          acc[m][q] = __builtin_amdgcn_mfma_f32_16x16x32_bf16(af[m], bfr[q], acc[m][q], 0,0,0);
    }
    __syncthreads();
  }

  // epilogue: acc -> LDS tile [px 128][co 136]
  #pragma unroll
  for (int m=0;m<4;m++){
    const int co = chw + m*16 + lg*4;
    const ushort4 bb = *(const ushort4*)(biasb + co);
    const float bv0=b2f(bb.x), bv1=b2f(bb.y), bv2=b2f(bb.z), bv3=b2f(bb.w);
    #pragma unroll
    for (int q=0;q<4;q++){
      const int px = phw + q*16 + l16;
      float v0 = acc[m][q][0] + bv0;
      float v1 = acc[m][q][1] + bv1;
      float v2 = acc[m][q][2] + bv2;
      float v3 = acc[m][q][3] + bv3;
      if (EPI==1){
        v0=fmaxf(v0,0.f); v1=fmaxf(v1,0.f); v2=fmaxf(v2,0.f); v3=fmaxf(v3,0.f);
      } else if (EPI==2){
        v0 = 1.f/(1.f+__expf(-v0)); v1 = 1.f/(1.f+__expf(-v1));
        v2 = 1.f/(1.f+__expf(-v2)); v3 = 1.f/(1.f+__expf(-v3));
      } else if (EPI==3 || EPI==4){
        const ushort4 sv = *(const ushort4*)(swp + (long)n*sw_n + (long)y*sw_y + (long)px*256 + cb*128 + co);
        v0 *= b2f(sv.x); v1 *= b2f(sv.y); v2 *= b2f(sv.z); v3 *= b2f(sv.w);
        v0 = v0>=0.f? v0 : 0.2f*v0;  v1 = v1>=0.f? v1 : 0.2f*v1;
        v2 = v2>=0.f? v2 : 0.2f*v2;  v3 = v3>=0.f? v3 : 0.2f*v3;
      }
      ushort4 ov; ov.x=f2b(v0); ov.y=f2b(v1); ov.z=f2b(v2); ov.w=f2b(v3);
      *(ushort4*)(ls + px*136 + co) = ov;
    }
  }
  __syncthreads();
  if (EPI == 4){
    // fused: out[n][c][y][:] = x + dx3, NCHW, coalesced per co row
    const int m2 = (int)flagp[0];
    const int co = tid>>1, hf2 = tid&1;
    const long xoff = (((long)n*256 + cb*128 + co)*H_ + y)*W_ + hf2*64;
    const u16* lrow = ls + (hf2*64)*136 + co;
    if (m2){
      const float* xf = (const float*)xres;
      float* of = (float*)outF;
      #pragma unroll
      for (int i=0;i<16;i++){
        const float4 xv = *(const float4*)(xf + xoff + i*4);
        float4 ov;
        ov.x = xv.x + b2f(lrow[(i*4+0)*136]);
        ov.y = xv.y + b2f(lrow[(i*4+1)*136]);
        ov.z = xv.z + b2f(lrow[(i*4+2)*136]);
        ov.w = xv.w + b2f(lrow[(i*4+3)*136]);
        *(float4*)(of + xoff + i*4) = ov;
      }
    } else {
      const u16* xu = (const u16*)xres;
      u16* ou = (u16*)outF;
      #pragma unroll
      for (int i=0;i<8;i++){
        const bf16x8 xv = *(const bf16x8*)(xu + xoff + i*8);
        bf16x8 ov;
        #pragma unroll
        for (int e=0;e<8;e++)
          ov[e] = (short)f2b(b2f((u16)xv[e]) + b2f(lrow[(i*8+e)*136]));
        *(bf16x8*)(ou + xoff + i*8) = ov;
      }
    }
  } else {
    const int row = tid>>1, hf = tid&1;
    u16* og = outb + (long)row*out_px + cb*128 + hf*64;
    #pragma unroll
    for (int i=0;i<8;i++)
      *(int4*)(og + i*8) = *(const int4*)(ls + row*136 + hf*64 + i*8);
    if (EPI == 3){
      // fused BN2 partial sums; part layout [c 256][w 256] (+65536 for sq)
      if (tid < 128){
        const int co = tid;
        float s = 0.f, q = 0.f;
        for (int px=0; px<128; ++px){
          const float v = b2f(ls[px*136 + co]);
          s += v; q += v*v;
        }
        const int cidx = cb*128 + co, w = n*128 + y;
        partp[(long)cidx*256 + w] = s;
        partp[65536L + (long)cidx*256 + w] = q;
      }
    }
  }
}

// ---------------- FUSED gw-conv + BN-affine + dynamic depthwise (v6 + xh LDS tile) ----------------
// 256 threads. Block = 144co x 128px (16 channels), BK=64, 18 K-steps.
// 4 waves 1M x 4N (144x32 wave tile, acc[9][2]=72 AGPR, VGPR ~68 -> 3 waves/SIMD).
// NEW: xh halo tile [3][130][16ch] (12.5KB) pre-loaded via global_load_lds BEFORE the
// K-loop (drains under step-0's barrier, free); depthwise reads LDS, not 9-tap global.
// LDS 50,496 B -> still 3 blocks/CU.
__global__ __launch_bounds__(256, 2)
void k_convdw(const u16* __restrict__ h1,      // padded [n][130][130][128]
              const u16* __restrict__ wp,      // [2304][9][128]
              const u16* __restrict__ bp,      // [2304] (co''=c*9+k order)
              const u16* __restrict__ xh,      // padded [n][130][130][256] (pre-BN act)
              const float2* __restrict__ ss,   // BN (scale, shift)
              u16* __restrict__ dd)            // [n][16384][256]
{
  __shared__ u16 ls[25248];   // staging A[0,9216) B[9216,17408); ct[144][132]=[0,19008); xh[19008,25248)
  u16* lsA = ls;
  u16* lsB = ls + 9216;
  u16* xtile = ls + 19008;    // [3][130][16]

  const int bx = blockIdx.x, mt = blockIdx.y, n = blockIdx.z;   // mt in [0,16)
  const int y = ((bx&7)<<4) | (bx>>3);      // XCD-band swizzle (bijective, 128%8==0)
  const int tid = threadIdx.x;
  const int wave = tid >> 6, lane = tid & 63;
  const int l16 = lane & 15, lg = lane >> 4;
  const int wn = wave * 32;           // px offset of wave

  const u16* wb = wp + (long)mt*144*1152;

  // pre-issue xh halo tile loads: rows y-1..y+1 (padded y..y+2), 130 x, 16 ch
  {
    const u16* xb = xh + ((long)n*PH + y)*PH*256 + mt*16;
    #pragma unroll
    for (int i=0;i<4;i++){
      const int q = i*256 + tid;          // 780 chunks of 16B
      if (q < 780){
        const int h = q & 1, pos = q >> 1;
        const int r = pos/130, xx = pos - r*130;
        gload16(xb + ((long)r*PH + xx)*256 + h*8, xtile + q*8);
      }
    }
  }

  f32x4 acc[9][2];
  #pragma unroll
  for (int m=0;m<9;m++){ acc[m][0]=(f32x4){0,0,0,0}; acc[m][1]=(f32x4){0,0,0,0}; }

  for (int s=0; s<18; ++s){
    const int tap = s >> 1;
    const int k0  = (s & 1) * 64;
    const int dy = tap/3 - 1, dx = tap%3 - 1;
    const u16* wsrc = wb + tap*128 + k0;
    const u16* bsrc = h1 + (((long)n*PH + (y+dy+1))*PH + (dx+1))*128 + k0;
    // stage A: 144 rows x 64 ci = 1152 chunks (4 x 256 + 128)
    #pragma unroll
    for (int i=0;i<4;i++){
      const int g = i*256 + tid;
      const int r = g>>3, c = g&7, sp = c ^ (r&7);
      gload16(wsrc + (long)r*1152 + sp*8, lsA + g*8);
    }
    if (tid < 128){
      const int g = 1024 + tid;
      const int r = g>>3, c = g&7, sp = c ^ (r&7);
      gload16(wsrc + (long)r*1152 + sp*8, lsA + g*8);
    }
    // stage B: 128 px x 64 ci = 1024 chunks (4 x 256)
    #pragma unroll
    for (int i=0;i<4;i++){
      const int g = i*256 + tid;
      const int p = g>>3, c = g&7, sp = c ^ (p&7);
      gload16(bsrc + (long)p*128 + sp*8, lsB + g*8);
    }
    __syncthreads();
    #pragma unroll
    for (int kk=0;kk<2;kk++){
      const int kc = kk*4 + lg;
      bf16x8 bfr[2];
      #pragma unroll
      for (int q=0;q<2;q++){
        const int rb = wn + q*16 + l16;
        bfr[q] = *(const bf16x8*)(lsB + rb*64 + ((kc ^ (rb&7))<<3));
      }
      #pragma unroll
      for (int m=0;m<9;m++){
        const int ra = m*16 + l16;
        const bf16x8 a = *(const bf16x8*)(lsA + ra*64 + ((kc ^ (ra&7))<<3));
        acc[m][0] = __builtin_amdgcn_mfma_f32_16x16x32_bf16(a, bfr[0], acc[m][0], 0,0,0);
        acc[m][1] = __builtin_amdgcn_mfma_f32_16x16x32_bf16(a, bfr[1], acc[m][1], 0,0,0);
      }
    }
    __syncthreads();
  }

  // ---- epilogue 1: cw + bias -> ct[144][132] (all 4 waves, disjoint px) ----
  u16* ct = ls;
  #pragma unroll
  for (int m=0;m<9;m++){
    const int r0 = m*16 + lg*4;
    const ushort4 bb = *(const ushort4*)(bp + mt*144 + r0);
    const float bv0=b2f(bb.x), bv1=b2f(bb.y), bv2=b2f(bb.z), bv3=b2f(bb.w);
    #pragma unroll
    for (int q=0;q<2;q++){
      const int px = wn + q*16 + l16;
      ct[(r0+0)*132 + px] = f2b(acc[m][q][0] + bv0);
      ct[(r0+1)*132 + px] = f2b(acc[m][q][1] + bv1);
      ct[(r0+2)*132 + px] = f2b(acc[m][q][2] + bv2);
      ct[(r0+3)*132 + px] = f2b(acc[m][q][3] + bv3);
    }
  }
  __syncthreads();

  // ---- epilogue 2: depthwise from LDS. cl = tid&15 channel, xg = tid>>4 ----
  const int cl = tid & 15;
  const int c  = mt*16 + cl;
  const float2 sc = ss[c];
  const int xg = tid >> 4;
  #pragma unroll
  for (int i=0;i<8;i++){
    const int x = i*16 + xg;
    float a = 0.f;
    #pragma unroll
    for (int k=0;k<9;k++){
      const int ddy = k/3-1, ddx = k%3-1;
      const int gy = y+ddy, gx = x+ddx;
      if ((unsigned)gy < 128u && (unsigned)gx < 128u){
        const float xv = b2f(xtile[((ddy+1)*130 + (gx+1))*16 + cl]);
        const float w  = b2f(ct[(cl*9+k)*132 + x]);
        a += (xv*sc.x + sc.y) * w;
      }
    }
    dd[(((long)n*PX) + (long)y*W_ + x)*256 + c] = f2b(a);
  }
}

// ---------------- BN stage 2 (stage 1 fused into producers; part = [c][w] + sq at +65536) ----------------
__global__ void k_bnstat2(const float* __restrict__ part, const void* __restrict__ g,
                          const void* __restrict__ b, const u32* __restrict__ flag,
                          float2* __restrict__ st)
{
  const int m = (int)flag[0];
  const int c = threadIdx.x;
  float s=0.f,q=0.f;
  for (int w=0;w<256;w++){ s += part[(long)c*256 + w]; q += part[65536L + (long)c*256 + w]; }
  const float mean = s*(1.f/32768.f);
  float v = q*(1.f/32768.f) - mean*mean;
  v = fmaxf(v, 0.f);
  const float sc = ldv(g,c,m) / sqrtf(v + 1e-5f);
  st[c] = make_float2(sc, ldv(b,c,m) - mean*sc);
}

// ---------------- weight prepacks (mode-aware loads) ----------------
__global__ void k_prep_w1(const void* a,const void* b,const void* c,const void* d,
                          const void* ba,const void* bb,const void* bc,const void* bd,
                          const u32* flag, u16* w1p, u16* bp1)
{
  const int m = (int)flag[0];
  const int idx = blockIdx.x*256 + threadIdx.x;     // 294912 = 4*128*9*64
  if (idx < 294912){
    const int ci = idx & 63, r = (idx>>6)%9, co = (idx/576)%128, brn = idx/73728;
    const void* w = brn==0?a:brn==1?b:brn==2?c:d;
    u16 v = 0;
    if (ci < 35) v = f2b(ldv(w, ((long)co*35 + ci)*9 + r, m));
    w1p[idx] = v;
  }
  if (idx < 512){
    const int brn = idx>>7, co = idx&127;
    const void* bb2 = brn==0?ba:brn==1?bb:brn==2?bc:bd;
    bp1[idx] = f2b(ldv(bb2, co, m));
  }
}

// gw weights: native [co''][ci 128][tap 9] -> [co''][tap][ci], COALESCED via LDS.
__global__ void k_prep_gw(const void* __restrict__ w2, const void* __restrict__ b2,
                          const u32* __restrict__ flag,
                          u16* __restrict__ w2p, u16* __restrict__ bp)
{
  __shared__ u16 lt[2304];
  const int m = (int)flag[0];
  const int b = blockIdx.x;            // [0,1152)
  const int t = threadIdx.x;
  #pragma unroll
  for (int i=0;i<9;i++){
    const int g = i*256 + t;           // [0,2304)
    const long src = (long)b*2304 + g; // flat native order (coalesced read)
    const int lco = g/1152, rem = g - lco*1152;
    const int ci = rem/9, tap = rem - ci*9;
    lt[lco*1152 + tap*128 + ci] = f2b(ldv(w2, src, m));
  }
  __syncthreads();
  #pragma unroll
  for (int i=0;i<9;i++){
    const int g = i*256 + t;
    w2p[(long)b*2304 + g] = lt[g];     // coalesced write in target order
  }
  if (b < 9){
    const int bi = b*256 + t;
    if (bi < 2304) bp[bi] = f2b(ldv(b2, bi, m));
  }
}

// se weights: per branch native [co 256][ci 128][tap 9] -> [brn][co][tap][ci], coalesced
__global__ void k_prep_se(const void* wa, const void* wb, const void* ba, const void* bb,
                          const u32* flag, u16* w2p, u16* bp)
{
  __shared__ u16 lt[2304];
  const int m = (int)flag[0];
  const int b = blockIdx.x;            // [0,256): brn = b>>7, co-pair = b&127
  const int brn = b >> 7;
  const void* w = brn ? wb : wa;
  const int t = threadIdx.x;
  #pragma unroll
  for (int i=0;i<9;i++){
    const int g = i*256 + t;
    const long src = (long)(b&127)*2304 + g;
    const int lco = g/1152, rem = g - lco*1152;
    const int ci = rem/9, tap = rem - ci*9;
    lt[lco*1152 + tap*128 + ci] = f2b(ldv(w, src, m));
  }
  __syncthreads();
  #pragma unroll
  for (int i=0;i<9;i++){
    const int g = i*256 + t;
    w2p[(long)b*2304 + g] = lt[g];
  }
  if ((b & 127) == 0)
    bp[brn*256 + t] = f2b(ldv(brn?bb:ba, t, m));
}

__global__ void k_prep_c(const void* c1w, const void* c1b, const void* c3w, const void* c3b,
                         const u32* flag, u16* c1wp, u16* c1bp, u16* c3wp, u16* c3bp)
{
  const int m = (int)flag[0];
  const int idx = blockIdx.x*256 + threadIdx.x;     // 65536
  if (idx < 65536){
    c1wp[idx] = f2b(ldv(c1w, idx, m));
    c3wp[idx] = f2b(ldv(c3w, idx, m));
  }
  if (idx < 256){
    c1bp[idx] = f2b(ldv(c1b, idx, m));
    c3bp[idx] = f2b(ldv(c3b, idx, m));
  }
}

// ---------------- input transposes (mode-aware) ----------------
__global__ __launch_bounds__(256)
void k_seg_t(const void* __restrict__ seg, const u32* __restrict__ flag,
             u16* __restrict__ segt)
{
  __shared__ u16 lt[8192];     // [x 128][ci 64]
  const int m = (int)flag[0];
  const int y = blockIdx.x, n = blockIdx.y, t = threadIdx.x;
  for (int i=t;i<8192;i+=256) lt[i]=0;
  __syncthreads();
  for (int idx=t; idx<128*35; idx+=256){
    const int x = idx/35, ci = idx - x*35;
    lt[x*64+ci] = f2b(ldv(seg, (((long)n*35 + ci)*256 + 2*y)*256 + 2*x, m));
  }
  __syncthreads();
  const int x = t>>1, hf = t&1;
  u16* o = segt + (((long)n*PH + (y+1))*PH + (x+1))*64 + hf*32;
  #pragma unroll
  for (int i=0;i<4;i++) *(int4*)(o + i*8) = *(const int4*)&lt[x*64 + hf*32 + i*8];
}

// x NCHW -> padded NHWC + fused BN1 partial sums; grid (128 y, 2 n, 4 cb)
__global__ __launch_bounds__(256)
void k_x_t(const void* __restrict__ x, const u32* __restrict__ flag,
           u16* __restrict__ xt, float* __restrict__ part)
{
  __shared__ u16 lt[128*72];
  const int m = (int)flag[0];
  const int y = blockIdx.x, n = blockIdx.y, cb = blockIdx.z;
  const int t = threadIdx.x;
  const long base = ((long)n*256 + cb*64)*PX + (long)y*W_;
  if (m){
    const float* xf = (const float*)x + base;
    #pragma unroll
    for (int i=0;i<8;i++){
      const int q = i*256 + t;          // 2048 float4
      const int c = q>>5, x4 = (q&31)*4;
      const float4 v = *(const float4*)(xf + (long)c*PX + x4);
      lt[(x4+0)*72 + c] = f2b(v.x);
      lt[(x4+1)*72 + c] = f2b(v.y);
      lt[(x4+2)*72 + c] = f2b(v.z);
      lt[(x4+3)*72 + c] = f2b(v.w);
    }
  } else {
    const u16* xu = (const u16*)x + base;
    #pragma unroll
    for (int i=0;i<4;i++){
      const int q = i*256 + t;          // 1024 ushort8
      const int c = q>>4, x8 = (q&15)*8;
      const bf16x8 v = *(const bf16x8*)(xu + (long)c*PX + x8);
      #pragma unroll
      for (int e=0;e<8;e++) lt[(x8+e)*72 + c] = (u16)v[e];
    }
  }
  __syncthreads();
  const int xx = t>>1, hf = t&1;
  u16* o = xt + (((long)n*PH + (y+1))*PH + (xx+1))*256 + cb*64 + hf*32;
  #pragma unroll
  for (int i=0;i<4;i++) *(int4*)(o+i*8) = *(const int4*)&lt[xx*72 + hf*32 + i*8];
  // fused BN1 partial sums; part layout [c 256][w 256] (+65536 for sq)
  if (t < 64){
    float s = 0.f, q = 0.f;
    for (int xi=0; xi<128; ++xi){
      const float v = b2f(lt[xi*72 + t]);
      s += v; q += v*v;
    }
    const int cidx = cb*64 + t, w = n*128 + y;
    part[(long)cidx*256 + w] = s;
    part[65536L + (long)cidx*256 + w] = q;
  }
}

extern "C" void kernel_launch(void* const* d_in, const int* in_sizes, int n_in,
                              void* d_out, int out_size, void* d_ws, size_t ws_size,
                              hipStream_t stream)
{
  (void)in_sizes; (void)n_in; (void)out_size; (void)ws_size;
  const void* x      = d_in[0];
  const void* seg    = d_in[1];
  const void* gw1_w1 = d_in[2];
  const void* gw1_b1 = d_in[3];
  const void* gw1_w2 = d_in[4];
  const void* gw1_b2 = d_in[5];
  const void* gw2_w1 = d_in[6];
  const void* gw2_b1 = d_in[7];
  const void* gw2_w2 = d_in[8];
  const void* gw2_b2 = d_in[9];
  const void* se1_w1 = d_in[10];
  const void* se1_b1 = d_in[11];
  const void* se1_w2 = d_in[12];
  const void* se1_b2 = d_in[13];
  const void* se2_w1 = d_in[14];
  const void* se2_b1 = d_in[15];
  const void* se2_w2 = d_in[16];
  const void* se2_b2 = d_in[17];
  const void* c1w = d_in[18];
  const void* c1b = d_in[19];
  const void* c3w = d_in[20];
  const void* c3b = d_in[21];
  const void* bn1g = d_in[22];
  const void* bn1b = d_in[23];
  const void* bn2g = d_in[24];
  const void* bn2b = d_in[25];
  u16* ws = (u16*)d_ws;

  // workspace layout (u16 element offsets), peak = 59,882,112 u16 = 119.8 MB
  u16* segt  = ws;                       // 2,163,200
  u16* xt    = ws + 2163200L;            // 8,652,800  (= t1, serialized overlay)
  u16* t1    = xt;
  u16* dd    = ws + 10816000L;           // 8,388,608
  u16* sw1   = ws + 19204608L;           // 8,388,608
  u16* sw2   = ws + 27593216L;           // 8,388,608
  u16* w1p   = ws + 35981824L;           // 294,912
  u16* bp1   = ws + 36276736L;           // 512
  u16* w2pg1 = ws + 36277248L;           // 2,654,208
  u16* w2pg2 = ws + 38931456L;           // 2,654,208
  u16* bpg   = ws + 41585664L;           // 4,608
  u16* w2ps  = ws + 41590272L;           // 589,824
  u16* bps   = ws + 42180096L;           // 512
  u16* c1wp  = ws + 42180608L;           // 65,536
  u16* c1bp  = ws + 42246144L;           // 256
  u16* c3wp  = ws + 42246400L;           // 65,536
  u16* c3bp  = ws + 42311936L;           // 256
  float*  part = (float*)(ws + 42312192L);   // 131,072 f32 (262,144 u16)
  float2* st1  = (float2*)(ws + 42574336L);  // 256 float2 (1,024 u16)
  float2* st2  = (float2*)(ws + 42575360L);  // 256 float2 (1,024 u16)
  u32*    flag = (u32*)(ws + 42576384L);     // 1 u32 (+pad)
  u16* h1t   = ws + 42576512L;           // 17,305,600 [4 branches x 2*130*130*128]

  // zero pads: segt memset (small) + h1t border-only kernel
  hipMemsetAsync(segt, 0, 4326400ULL, stream);
  k_zpad<<<dim3(8),256,0,stream>>>(h1t);

  // dtype autodetect, then prepacks + transposes
  k_detect<<<dim3(1),256,0,stream>>>((const u32*)x, flag);
  k_prep_w1<<<dim3(1152),256,0,stream>>>(gw1_w1,gw2_w1,se1_w1,se2_w1,
                                         gw1_b1,gw2_b1,se1_b1,se2_b1, flag, w1p, bp1);
  k_prep_gw<<<dim3(1152),256,0,stream>>>(gw1_w2, gw1_b2, flag, w2pg1, bpg);
  k_prep_gw<<<dim3(1152),256,0,stream>>>(gw2_w2, gw2_b2, flag, w2pg2, bpg+2304);
  k_prep_se<<<dim3(256),256,0,stream>>>(se1_w2, se2_w2, se1_b2, se2_b2, flag, w2ps, bps);
  k_prep_c<<<dim3(256),256,0,stream>>>(c1w, c1b, c3w, c3b, flag, c1wp, c1bp, c3wp, c3bp);
  k_seg_t<<<dim3(128,2),256,0,stream>>>(seg, flag, segt);
  k_x_t<<<dim3(128,2,4),256,0,stream>>>(x, flag, xt, part);   // + BN1 partial sums

  // branch conv1 (4 branches, relu) : segmap -> h1t[br]
  k_convgemm<64,9,1><<<dim3(128,4,2),256,0,stream>>>(
      segt, w1p, bp1, nullptr, h1t, 1,
      0L, 73728L, 128, 4326400L,
      1081600L, 8320, 8384,
      2163200L, 16640L, 128, 16768, 0L, 0,
      nullptr, nullptr, nullptr, nullptr);

  // se conv2 (2 branches, sigmoid) : h1t[2],h1t[3] -> sw1, sw2
  k_convgemm<128,9,2><<<dim3(128,4,2),256,0,stream>>>(
      h1t + 2*4326400L, w2ps, bps, nullptr, sw1, 2,
      4326400L, 294912L, 256, 8388608L,
      2163200L, 16640, 16768,
      4194304L, 32768L, 256, 0, 0L, 0,
      nullptr, nullptr, nullptr, nullptr);

  // BN1 stage 2 (stage 1 fused into k_x_t)
  k_bnstat2<<<dim3(1),256,0,stream>>>(part, bn1g, bn1b, flag, st1);

  // fused gw conv + BN1 + depthwise, branch 1: h1t[0] x xt -> dd
  k_convdw<<<dim3(128,16,2),256,0,stream>>>(h1t, w2pg1, bpg, xt, st1, dd);

  // 1x1 conv #1 (+bias, *sw1, lrelu) -> t1 (padded) + BN2 partial sums
  k_convgemm<256,1,3><<<dim3(128,2,2),256,0,stream>>>(
      dd, c1wp, c1bp, sw1, t1, 2,
      0L, 0L, 0, 0L,
      4194304L, 32768, 0,
      4326400L, 33280L, 256, 33536, 4194304L, 32768,
      nullptr, nullptr, nullptr, part);

  // BN2 stage 2
  k_bnstat2<<<dim3(1),256,0,stream>>>(part, bn2g, bn2b, flag, st2);

  // fused gw conv + BN2 + depthwise, branch 2: h1t[1] x t1 -> dd
  k_convdw<<<dim3(128,16,2),256,0,stream>>>(h1t + 4326400L, w2pg2, bpg+2304, t1, st2, dd);

  // 1x1 conv #2 (+bias, *sw2, lrelu) + fused residual add -> d_out (NCHW)
  k_convgemm<256,1,4><<<dim3(128,2,2),256,0,stream>>>(
      dd, c3wp, c3bp, sw2, dd, 2,
      0L, 0L, 0, 0L,
      4194304L, 32768, 0,
      0L, 0L, 256, 0, 4194304L, 32768,
      x, flag, d_out, nullptr);
}

// Round 15
// 592.625 us; speedup vs baseline: 1.3436x; 1.0063x over previous
//
#include <hip/hip_runtime.h>
#include <hip/hip_bf16.h>

typedef unsigned short u16;
typedef unsigned int u32;
typedef __attribute__((ext_vector_type(8))) short bf16x8;
typedef __attribute__((ext_vector_type(4))) float f32x4;
typedef __attribute__((address_space(3))) u32 lds_u32;
typedef const __attribute__((address_space(1))) u32 glb_u32;

#define H_ 128
#define W_ 128
#define PX 16384
#define PH 130

__device__ __forceinline__ float b2f(u16 h){ u32 u = ((u32)h)<<16; return __uint_as_float(u); }
__device__ __forceinline__ u16 f2b(float f){
  u32 u = __float_as_uint(f);
  u32 r = (u + 0x7fffu + ((u>>16)&1u)) >> 16;
  return (u16)r;
}
// mode: 1 = inputs are float32, 0 = inputs are bf16
__device__ __forceinline__ float ldv(const void* p, long i, int m){
  return m ? ((const float*)p)[i] : b2f(((const u16*)p)[i]);
}
__device__ __forceinline__ void gload16(const u16* g, u16* l){
  __builtin_amdgcn_global_load_lds((glb_u32*)g, (lds_u32*)l, 16, 0, 0);
}

// ---------------- dtype autodetect ----------------
__global__ void k_detect(const u32* __restrict__ xw, u32* __restrict__ flag){
  __shared__ int cnt[256];
  const int t = threadIdx.x;
  int c = 0;
  #pragma unroll
  for (int i=0;i<4;i++){
    const u32 w = xw[t*4+i];
    const u32 e = ((w & 0xFFFFu) >> 7) & 0xFF;
    if (e >= 90 && e <= 140) c++;     // bf16 low-half exponent range for N(0,1)
  }
  cnt[t] = c; __syncthreads();
  for (int s=128;s>0;s>>=1){ if (t<s) cnt[t]+=cnt[t+s]; __syncthreads(); }
  if (t==0) flag[0] = (cnt[0] < 512) ? 1u : 0u;   // few hits -> f32 data
}

// ---------------- border-zero for h1t pads (replaces 34.6MB memset) ----------------
__global__ void k_zpad(u16* __restrict__ h1t){
  const int p = blockIdx.x;            // 8 planes: br = p>>1, n = p&1
  u16* base = h1t + (long)p*2163200L;  // [130][130][128]
  const int t = threadIdx.x;
  const int4 z = make_int4(0,0,0,0);
  for (int idx=t; idx<8256; idx+=256){
    long off;
    if (idx < 2080)       off = (long)idx*8;                                   // row 0
    else if (idx < 4160)  off = 2146560L + (long)(idx-2080)*8;                 // row 129
    else if (idx < 6208){ const int r = 1 + (idx-4160)/16, w = (idx-4160)%16;  // col 0
                          off = (long)r*16640 + w*8; }
    else {                const int r = 1 + (idx-6208)/16, w = (idx-6208)%16;  // col 129
                          off = (long)r*16640 + 16512 + w*8; }
    *(int4*)(base + off) = z;
  }
}

// ---------------- implicit-GEMM conv kernel (conv1 / se / 1x1) ----------------
// EPI: 0=bias, 1=bias+relu, 2=bias+sigmoid, 3=(bias)*sw+lrelu ->NHWC (+BN partial sums),
//      4=EPI3 math then fused residual add + NCHW write to outF
// MINW: min waves/EU (3 -> 3 blocks/CU; regs 64 AGPR + ~70 VGPR fit)
template<int CIN, int NTAPS, int EPI, int MINW>
__global__ __launch_bounds__(256, MINW)
void k_convgemm(const u16* __restrict__ inp, const u16* __restrict__ wp,
                const u16* __restrict__ bias, const u16* __restrict__ swp,
                u16* __restrict__ outp, int nbco,
                long in_br, long w_br, int bias_br, long out_br,
                long in_n, int in_row, int in_x0,
                long out_n, long out_y, int out_px, int out_x0,
                long sw_n, int sw_y,
                const void* __restrict__ xres, const u32* __restrict__ flagp,
                void* __restrict__ outF, float* __restrict__ partp)
{
  __shared__ u16 ls[17408];          // A:[0,8192) B:[8192,16384); epilogue tile [128][136]
  u16* lsA = ls;
  u16* lsB = ls + 8192;

  const int bx  = blockIdx.x;
  // XCD-aware y swizzle for the 3x3 convs (halo reuse in per-XCD L2); grid.x==128
  const int y   = (NTAPS==9) ? (((bx&7)<<4) | (bx>>3)) : bx;
  const int br  = blockIdx.y / nbco;
  const int cb  = blockIdx.y - br*nbco;
  const int n   = blockIdx.z;
  const int tid = threadIdx.x;
  const int wave = tid >> 6, lane = tid & 63;
  const int l16 = lane & 15, lg = lane >> 4;
  const int chw = (wave >> 1) * 64;   // co half
  const int phw = (wave & 1) * 64;    // px half

  const u16* inb   = inp + (long)br*in_br + (long)n*in_n + in_x0 + (long)y*in_row;
  const u16* wb    = wp  + (long)br*w_br + (long)cb*128*(NTAPS*CIN);
  const u16* biasb = bias + (long)br*bias_br + cb*128;
  u16* outb = outp + (long)br*out_br + (long)n*out_n + out_x0 + (long)y*out_y;

  f32x4 acc[4][4];
  #pragma unroll
  for (int m=0;m<4;m++)
    #pragma unroll
    for (int q=0;q<4;q++) acc[m][q] = (f32x4){0.f,0.f,0.f,0.f};

  const int NSTEP = NTAPS*(CIN/64);
  for (int step=0; step<NSTEP; ++step){
    const int tap = step/(CIN/64);
    const int k0  = (step - tap*(CIN/64))*64;
    const int dy = (NTAPS==1)?0:(tap/3-1);
    const int dx = (NTAPS==1)?0:(tap%3-1);
    const u16* wsrc = wb  + tap*CIN + k0;
    const u16* bsrc = inb + (long)dy*in_row + dx*CIN + k0;
    #pragma unroll
    for (int i=0;i<4;i++){
      const int idx = (wave*4+i)*64 + lane;
      const int r = idx>>3, c = idx&7;
      const int cc = c ^ (r&7);
      gload16(wsrc + (long)r*(NTAPS*CIN) + cc*8, lsA + (wave*4+i)*512);
    }
    #pragma unroll
    for (int i=0;i<4;i++){
      const int idx = (wave*4+i)*64 + lane;
      const int r = idx>>3, c = idx&7;
      const int cc = c ^ (r&7);
      gload16(bsrc + (long)r*CIN + cc*8, lsB + (wave*4+i)*512);
    }
    __syncthreads();
    #pragma unroll
    for (int kk=0;kk<2;kk++){
      bf16x8 af[4], bfr[4];
      const int kc = kk*4 + lg;
      #pragma unroll
      for (int m=0;m<4;m++){
        const int r = chw + m*16 + l16;
        af[m] = *(const bf16x8*)(lsA + r*64 + ((kc ^ (r&7))<<3));
      }
      #pragma unroll
      for (int q=0;q<4;q++){
        const int r = phw + q*16 + l16;
        bfr[q] = *(const bf16x8*)(lsB + r*64 + ((kc ^ (r&7))<<3));
      }
      #pragma unroll
      for (int m=0;m<4;m++)
        #pragma unroll
        for (int q=0;q<4;q++)
          acc[m][q] = __builtin_amdgcn_mfma_f32_16x16x32_bf16(af[m], bfr[q], acc[m][q], 0,0,0);
    }
    __syncthreads();
  }

  // epilogue: acc -> LDS tile [px 128][co 136]
  #pragma unroll
  for (int m=0;m<4;m++){
    const int co = chw + m*16 + lg*4;
    const ushort4 bb = *(const ushort4*)(biasb + co);
    const float bv0=b2f(bb.x), bv1=b2f(bb.y), bv2=b2f(bb.z), bv3=b2f(bb.w);
    #pragma unroll
    for (int q=0;q<4;q++){
      const int px = phw + q*16 + l16;
      float v0 = acc[m][q][0] + bv0;
      float v1 = acc[m][q][1] + bv1;
      float v2 = acc[m][q][2] + bv2;
      float v3 = acc[m][q][3] + bv3;
      if (EPI==1){
        v0=fmaxf(v0,0.f); v1=fmaxf(v1,0.f); v2=fmaxf(v2,0.f); v3=fmaxf(v3,0.f);
      } else if (EPI==2){
        v0 = 1.f/(1.f+__expf(-v0)); v1 = 1.f/(1.f+__expf(-v1));
        v2 = 1.f/(1.f+__expf(-v2)); v3 = 1.f/(1.f+__expf(-v3));
      } else if (EPI==3 || EPI==4){
        const ushort4 sv = *(const ushort4*)(swp + (long)n*sw_n + (long)y*sw_y + (long)px*256 + cb*128 + co);
        v0 *= b2f(sv.x); v1 *= b2f(sv.y); v2 *= b2f(sv.z); v3 *= b2f(sv.w);
        v0 = v0>=0.f? v0 : 0.2f*v0;  v1 = v1>=0.f? v1 : 0.2f*v1;
        v2 = v2>=0.f? v2 : 0.2f*v2;  v3 = v3>=0.f? v3 : 0.2f*v3;
      }
      ushort4 ov; ov.x=f2b(v0); ov.y=f2b(v1); ov.z=f2b(v2); ov.w=f2b(v3);
      *(ushort4*)(ls + px*136 + co) = ov;
    }
  }
  __syncthreads();
  if (EPI == 4){
    // fused: out[n][c][y][:] = x + dx3, NCHW, coalesced per co row
    const int m2 = (int)flagp[0];
    const int co = tid>>1, hf2 = tid&1;
    const long xoff = (((long)n*256 + cb*128 + co)*H_ + y)*W_ + hf2*64;
    const u16* lrow = ls + (hf2*64)*136 + co;
    if (m2){
      const float* xf = (const float*)xres;
      float* of = (float*)outF;
      #pragma unroll
      for (int i=0;i<16;i++){
        const float4 xv = *(const float4*)(xf + xoff + i*4);
        float4 ov;
        ov.x = xv.x + b2f(lrow[(i*4+0)*136]);
        ov.y = xv.y + b2f(lrow[(i*4+1)*136]);
        ov.z = xv.z + b2f(lrow[(i*4+2)*136]);
        ov.w = xv.w + b2f(lrow[(i*4+3)*136]);
        *(float4*)(of + xoff + i*4) = ov;
      }
    } else {
      const u16* xu = (const u16*)xres;
      u16* ou = (u16*)outF;
      #pragma unroll
      for (int i=0;i<8;i++){
        const bf16x8 xv = *(const bf16x8*)(xu + xoff + i*8);
        bf16x8 ov;
        #pragma unroll
        for (int e=0;e<8;e++)
          ov[e] = (short)f2b(b2f((u16)xv[e]) + b2f(lrow[(i*8+e)*136]));
        *(bf16x8*)(ou + xoff + i*8) = ov;
      }
    }
  } else {
    const int row = tid>>1, hf = tid&1;
    u16* og = outb + (long)row*out_px + cb*128 + hf*64;
    #pragma unroll
    for (int i=0;i<8;i++)
      *(int4*)(og + i*8) = *(const int4*)(ls + row*136 + hf*64 + i*8);
    if (EPI == 3){
      // fused BN2 partial sums; part layout [c 256][w 256] (+65536 for sq)
      if (tid < 128){
        const int co = tid;
        float s = 0.f, q = 0.f;
        for (int px=0; px<128; ++px){
          const float v = b2f(ls[px*136 + co]);
          s += v; q += v*v;
        }
        const int cidx = cb*128 + co, w = n*128 + y;
        partp[(long)cidx*256 + w] = s;
        partp[65536L + (long)cidx*256 + w] = q;
      }
    }
  }
}

// ---------------- FUSED gw-conv + BN-affine + dynamic depthwise (v6 + xh LDS tile) ----------------
// 256 threads. Block = 144co x 128px (16 channels), BK=64, 18 K-steps.
// 4 waves 1M x 4N (144x32 wave tile, acc[9][2]=72 AGPR, VGPR ~68 -> 3 waves/SIMD).
// xh halo tile [3][130][16ch] pre-loaded via global_load_lds BEFORE the K-loop
// (drains under step-0's barrier, free); depthwise reads LDS. LDS 50,688 B -> 3 blocks/CU.
__global__ __launch_bounds__(256, 2)
void k_convdw(const u16* __restrict__ h1,      // padded [n][130][130][128]
              const u16* __restrict__ wp,      // [2304][9][128]
              const u16* __restrict__ bp,      // [2304] (co''=c*9+k order)
              const u16* __restrict__ xh,      // padded [n][130][130][256] (pre-BN act)
              const float2* __restrict__ ss,   // BN (scale, shift)
              u16* __restrict__ dd)            // [n][16384][256]
{
  __shared__ u16 ls[25248];   // staging A[0,9216) B[9216,17408); ct[144][132]=[0,19008); xh[19008,25248)
  u16* lsA = ls;
  u16* lsB = ls + 9216;
  u16* xtile = ls + 19008;    // [3][130][16]

  const int bx = blockIdx.x, mt = blockIdx.y, n = blockIdx.z;   // mt in [0,16)
  const int y = ((bx&7)<<4) | (bx>>3);      // XCD-band swizzle (bijective, 128%8==0)
  const int tid = threadIdx.x;
  const int wave = tid >> 6, lane = tid & 63;
  const int l16 = lane & 15, lg = lane >> 4;
  const int wn = wave * 32;           // px offset of wave

  const u16* wb = wp + (long)mt*144*1152;

  // pre-issue xh halo tile loads: rows y-1..y+1 (padded y..y+2), 130 x, 16 ch
  {
    const u16* xb = xh + ((long)n*PH + y)*PH*256 + mt*16;
    #pragma unroll
    for (int i=0;i<4;i++){
      const int q = i*256 + tid;          // 780 chunks of 16B
      if (q < 780){
        const int h = q & 1, pos = q >> 1;
        const int r = pos/130, xx = pos - r*130;
        gload16(xb + ((long)r*PH + xx)*256 + h*8, xtile + q*8);
      }
    }
  }

  f32x4 acc[9][2];
  #pragma unroll
  for (int m=0;m<9;m++){ acc[m][0]=(f32x4){0,0,0,0}; acc[m][1]=(f32x4){0,0,0,0}; }

  for (int s=0; s<18; ++s){
    const int tap = s >> 1;
    const int k0  = (s & 1) * 64;
    const int dy = tap/3 - 1, dx = tap%3 - 1;
    const u16* wsrc = wb + tap*128 + k0;
    const u16* bsrc = h1 + (((long)n*PH + (y+dy+1))*PH + (dx+1))*128 + k0;
    // stage A: 144 rows x 64 ci = 1152 chunks (4 x 256 + 128)
    #pragma unroll
    for (int i=0;i<4;i++){
      const int g = i*256 + tid;
      const int r = g>>3, c = g&7, sp = c ^ (r&7);
      gload16(wsrc + (long)r*1152 + sp*8, lsA + g*8);
    }
    if (tid < 128){
      const int g = 1024 + tid;
      const int r = g>>3, c = g&7, sp = c ^ (r&7);
      gload16(wsrc + (long)r*1152 + sp*8, lsA + g*8);
    }
    // stage B: 128 px x 64 ci = 1024 chunks (4 x 256)
    #pragma unroll
    for (int i=0;i<4;i++){
      const int g = i*256 + tid;
      const int p = g>>3, c = g&7, sp = c ^ (p&7);
      gload16(bsrc + (long)p*128 + sp*8, lsB + g*8);
    }
    __syncthreads();
    #pragma unroll
    for (int kk=0;kk<2;kk++){
      const int kc = kk*4 + lg;
      bf16x8 bfr[2];
      #pragma unroll
      for (int q=0;q<2;q++){
        const int rb = wn + q*16 + l16;
        bfr[q] = *(const bf16x8*)(lsB + rb*64 + ((kc ^ (rb&7))<<3));
      }
      #pragma unroll
      for (int m=0;m<9;m++){
        const int ra = m*16 + l16;
        const bf16x8 a = *(const bf16x8*)(lsA + ra*64 + ((kc ^ (ra&7))<<3));
        acc[m][0] = __builtin_amdgcn_mfma_f32_16x16x32_bf16(a, bfr[0], acc[m][0], 0,0,0);
        acc[m][1] = __builtin_amdgcn_mfma_f32_16x16x32_bf16(a, bfr[1], acc[m][1], 0,0,0);
      }
    }
    __syncthreads();
  }

  // ---- epilogue 1: cw + bias -> ct[144][132] (all 4 waves, disjoint px) ----
  u16* ct = ls;
  #pragma unroll
  for (int m=0;m<9;m++){
    const int r0 = m*16 + lg*4;
    const ushort4 bb = *(const ushort4*)(bp + mt*144 + r0);
    const float bv0=b2f(bb.x), bv1=b2f(bb.y), bv2=b2f(bb.z), bv3=b2f(bb.w);
    #pragma unroll
    for (int q=0;q<2;q++){
      const int px = wn + q*16 + l16;
      ct[(r0+0)*132 + px] = f2b(acc[m][q][0] + bv0);
      ct[(r0+1)*132 + px] = f2b(acc[m][q][1] + bv1);
      ct[(r0+2)*132 + px] = f2b(acc[m][q][2] + bv2);
      ct[(r0+3)*132 + px] = f2b(acc[m][q][3] + bv3);
    }
  }
  __syncthreads();

  // ---- epilogue 2: depthwise from LDS. cl = tid&15 channel, xg = tid>>4 ----
  const int cl = tid & 15;
  const int c  = mt*16 + cl;
  const float2 sc = ss[c];
  const int xg = tid >> 4;
  #pragma unroll
  for (int i=0;i<8;i++){
    const int x = i*16 + xg;
    float a = 0.f;
    #pragma unroll
    for (int k=0;k<9;k++){
      const int ddy = k/3-1, ddx = k%3-1;
      const int gy = y+ddy, gx = x+ddx;
      if ((unsigned)gy < 128u && (unsigned)gx < 128u){
        const float xv = b2f(xtile[((ddy+1)*130 + (gx+1))*16 + cl]);
        const float w  = b2f(ct[(cl*9+k)*132 + x]);
        a += (xv*sc.x + sc.y) * w;
      }
    }
    dd[(((long)n*PX) + (long)y*W_ + x)*256 + c] = f2b(a);
  }
}

// ---------------- BN stage 2 (stage 1 fused into producers; part = [c][w] + sq at +65536) ----------------
__global__ void k_bnstat2(const float* __restrict__ part, const void* __restrict__ g,
                          const void* __restrict__ b, const u32* __restrict__ flag,
                          float2* __restrict__ st)
{
  const int m = (int)flag[0];
  const int c = threadIdx.x;
  float s=0.f,q=0.f;
  for (int w=0;w<256;w++){ s += part[(long)c*256 + w]; q += part[65536L + (long)c*256 + w]; }
  const float mean = s*(1.f/32768.f);
  float v = q*(1.f/32768.f) - mean*mean;
  v = fmaxf(v, 0.f);
  const float sc = ldv(g,c,m) / sqrtf(v + 1e-5f);
  st[c] = make_float2(sc, ldv(b,c,m) - mean*sc);
}

// ---------------- weight prepacks (mode-aware loads) ----------------
__global__ void k_prep_w1(const void* a,const void* b,const void* c,const void* d,
                          const void* ba,const void* bb,const void* bc,const void* bd,
                          const u32* flag, u16* w1p, u16* bp1)
{
  const int m = (int)flag[0];
  const int idx = blockIdx.x*256 + threadIdx.x;     // 294912 = 4*128*9*64
  if (idx < 294912){
    const int ci = idx & 63, r = (idx>>6)%9, co = (idx/576)%128, brn = idx/73728;
    const void* w = brn==0?a:brn==1?b:brn==2?c:d;
    u16 v = 0;
    if (ci < 35) v = f2b(ldv(w, ((long)co*35 + ci)*9 + r, m));
    w1p[idx] = v;
  }
  if (idx < 512){
    const int brn = idx>>7, co = idx&127;
    const void* bb2 = brn==0?ba:brn==1?bb:brn==2?bc:bd;
    bp1[idx] = f2b(ldv(bb2, co, m));
  }
}

// gw weights: native [co''][ci 128][tap 9] -> [co''][tap][ci], COALESCED via LDS.
__global__ void k_prep_gw(const void* __restrict__ w2, const void* __restrict__ b2,
                          const u32* __restrict__ flag,
                          u16* __restrict__ w2p, u16* __restrict__ bp)
{
  __shared__ u16 lt[2304];
  const int m = (int)flag[0];
  const int b = blockIdx.x;            // [0,1152)
  const int t = threadIdx.x;
  #pragma unroll
  for (int i=0;i<9;i++){
    const int g = i*256 + t;           // [0,2304)
    const long src = (long)b*2304 + g; // flat native order (coalesced read)
    const int lco = g/1152, rem = g - lco*1152;
    const int ci = rem/9, tap = rem - ci*9;
    lt[lco*1152 + tap*128 + ci] = f2b(ldv(w2, src, m));
  }
  __syncthreads();
  #pragma unroll
  for (int i=0;i<9;i++){
    const int g = i*256 + t;
    w2p[(long)b*2304 + g] = lt[g];     // coalesced write in target order
  }
  if (b < 9){
    const int bi = b*256 + t;
    if (bi < 2304) bp[bi] = f2b(ldv(b2, bi, m));
  }
}

// se weights: per branch native [co 256][ci 128][tap 9] -> [brn][co][tap][ci], coalesced
__global__ void k_prep_se(const void* wa, const void* wb, const void* ba, const void* bb,
                          const u32* flag, u16* w2p, u16* bp)
{
  __shared__ u16 lt[2304];
  const int m = (int)flag[0];
  const int b = blockIdx.x;            // [0,256): brn = b>>7, co-pair = b&127
  const int brn = b >> 7;
  const void* w = brn ? wb : wa;
  const int t = threadIdx.x;
  #pragma unroll
  for (int i=0;i<9;i++){
    const int g = i*256 + t;
    const long src = (long)(b&127)*2304 + g;
    const int lco = g/1152, rem = g - lco*1152;
    const int ci = rem/9, tap = rem - ci*9;
    lt[lco*1152 + tap*128 + ci] = f2b(ldv(w, src, m));
  }
  __syncthreads();
  #pragma unroll
  for (int i=0;i<9;i++){
    const int g = i*256 + t;
    w2p[(long)b*2304 + g] = lt[g];
  }
  if ((b & 127) == 0)
    bp[brn*256 + t] = f2b(ldv(brn?bb:ba, t, m));
}

__global__ void k_prep_c(const void* c1w, const void* c1b, const void* c3w, const void* c3b,
                         const u32* flag, u16* c1wp, u16* c1bp, u16* c3wp, u16* c3bp)
{
  const int m = (int)flag[0];
  const int idx = blockIdx.x*256 + threadIdx.x;     // 65536
  if (idx < 65536){
    c1wp[idx] = f2b(ldv(c1w, idx, m));
    c3wp[idx] = f2b(ldv(c3w, idx, m));
  }
  if (idx < 256){
    c1bp[idx] = f2b(ldv(c1b, idx, m));
    c3bp[idx] = f2b(ldv(c3b, idx, m));
  }
}

// ---------------- input transposes (mode-aware) ----------------
__global__ __launch_bounds__(256)
void k_seg_t(const void* __restrict__ seg, const u32* __restrict__ flag,
             u16* __restrict__ segt)
{
  __shared__ u16 lt[8192];     // [x 128][ci 64]
  const int m = (int)flag[0];
  const int y = blockIdx.x, n = blockIdx.y, t = threadIdx.x;
  for (int i=t;i<8192;i+=256) lt[i]=0;
  __syncthreads();
  for (int idx=t; idx<128*35; idx+=256){
    const int x = idx/35, ci = idx - x*35;
    lt[x*64+ci] = f2b(ldv(seg, (((long)n*35 + ci)*256 + 2*y)*256 + 2*x, m));
  }
  __syncthreads();
  const int x = t>>1, hf = t&1;
  u16* o = segt + (((long)n*PH + (y+1))*PH + (x+1))*64 + hf*32;
  #pragma unroll
  for (int i=0;i<4;i++) *(int4*)(o + i*8) = *(const int4*)&lt[x*64 + hf*32 + i*8];
}

// x NCHW -> padded NHWC + fused BN1 partial sums; grid (128 y, 2 n, 4 cb)
__global__ __launch_bounds__(256)
void k_x_t(const void* __restrict__ x, const u32* __restrict__ flag,
           u16* __restrict__ xt, float* __restrict__ part)
{
  __shared__ u16 lt[128*72];
  const int m = (int)flag[0];
  const int y = blockIdx.x, n = blockIdx.y, cb = blockIdx.z;
  const int t = threadIdx.x;
  const long base = ((long)n*256 + cb*64)*PX + (long)y*W_;
  if (m){
    const float* xf = (const float*)x + base;
    #pragma unroll
    for (int i=0;i<8;i++){
      const int q = i*256 + t;          // 2048 float4
      const int c = q>>5, x4 = (q&31)*4;
      const float4 v = *(const float4*)(xf + (long)c*PX + x4);
      lt[(x4+0)*72 + c] = f2b(v.x);
      lt[(x4+1)*72 + c] = f2b(v.y);
      lt[(x4+2)*72 + c] = f2b(v.z);
      lt[(x4+3)*72 + c] = f2b(v.w);
    }
  } else {
    const u16* xu = (const u16*)x + base;
    #pragma unroll
    for (int i=0;i<4;i++){
      const int q = i*256 + t;          // 1024 ushort8
      const int c = q>>4, x8 = (q&15)*8;
      const bf16x8 v = *(const bf16x8*)(xu + (long)c*PX + x8);
      #pragma unroll
      for (int e=0;e<8;e++) lt[(x8+e)*72 + c] = (u16)v[e];
    }
  }
  __syncthreads();
  const int xx = t>>1, hf = t&1;
  u16* o = xt + (((long)n*PH + (y+1))*PH + (xx+1))*256 + cb*64 + hf*32;
  #pragma unroll
  for (int i=0;i<4;i++) *(int4*)(o+i*8) = *(const int4*)&lt[xx*72 + hf*32 + i*8];
  // fused BN1 partial sums; part layout [c 256][w 256] (+65536 for sq)
  if (t < 64){
    float s = 0.f, q = 0.f;
    for (int xi=0; xi<128; ++xi){
      const float v = b2f(lt[xi*72 + t]);
      s += v; q += v*v;
    }
    const int cidx = cb*64 + t, w = n*128 + y;
    part[(long)cidx*256 + w] = s;
    part[65536L + (long)cidx*256 + w] = q;
  }
}

extern "C" void kernel_launch(void* const* d_in, const int* in_sizes, int n_in,
                              void* d_out, int out_size, void* d_ws, size_t ws_size,
                              hipStream_t stream)
{
  (void)in_sizes; (void)n_in; (void)out_size; (void)ws_size;
  const void* x      = d_in[0];
  const void* seg    = d_in[1];
  const void* gw1_w1 = d_in[2];
  const void* gw1_b1 = d_in[3];
  const void* gw1_w2 = d_in[4];
  const void* gw1_b2 = d_in[5];
  const void* gw2_w1 = d_in[6];
  const void* gw2_b1 = d_in[7];
  const void* gw2_w2 = d_in[8];
  const void* gw2_b2 = d_in[9];
  const void* se1_w1 = d_in[10];
  const void* se1_b1 = d_in[11];
  const void* se1_w2 = d_in[12];
  const void* se1_b2 = d_in[13];
  const void* se2_w1 = d_in[14];
  const void* se2_b1 = d_in[15];
  const void* se2_w2 = d_in[16];
  const void* se2_b2 = d_in[17];
  const void* c1w = d_in[18];
  const void* c1b = d_in[19];
  const void* c3w = d_in[20];
  const void* c3b = d_in[21];
  const void* bn1g = d_in[22];
  const void* bn1b = d_in[23];
  const void* bn2g = d_in[24];
  const void* bn2b = d_in[25];
  u16* ws = (u16*)d_ws;

  // workspace layout (u16 element offsets), peak = 59,882,112 u16 = 119.8 MB
  u16* segt  = ws;                       // 2,163,200
  u16* xt    = ws + 2163200L;            // 8,652,800  (= t1, serialized overlay)
  u16* t1    = xt;
  u16* dd    = ws + 10816000L;           // 8,388,608
  u16* sw1   = ws + 19204608L;           // 8,388,608
  u16* sw2   = ws + 27593216L;           // 8,388,608
  u16* w1p   = ws + 35981824L;           // 294,912
  u16* bp1   = ws + 36276736L;           // 512
  u16* w2pg1 = ws + 36277248L;           // 2,654,208
  u16* w2pg2 = ws + 38931456L;           // 2,654,208
  u16* bpg   = ws + 41585664L;           // 4,608
  u16* w2ps  = ws + 41590272L;           // 589,824
  u16* bps   = ws + 42180096L;           // 512
  u16* c1wp  = ws + 42180608L;           // 65,536
  u16* c1bp  = ws + 42246144L;           // 256
  u16* c3wp  = ws + 42246400L;           // 65,536
  u16* c3bp  = ws + 42311936L;           // 256
  float*  part = (float*)(ws + 42312192L);   // 131,072 f32 (262,144 u16)
  float2* st1  = (float2*)(ws + 42574336L);  // 256 float2 (1,024 u16)
  float2* st2  = (float2*)(ws + 42575360L);  // 256 float2 (1,024 u16)
  u32*    flag = (u32*)(ws + 42576384L);     // 1 u32 (+pad)
  u16* h1t   = ws + 42576512L;           // 17,305,600 [4 branches x 2*130*130*128]

  // zero pads: segt memset (small) + h1t border-only kernel
  hipMemsetAsync(segt, 0, 4326400ULL, stream);
  k_zpad<<<dim3(8),256,0,stream>>>(h1t);

  // dtype autodetect, then prepacks + transposes
  k_detect<<<dim3(1),256,0,stream>>>((const u32*)x, flag);
  k_prep_w1<<<dim3(1152),256,0,stream>>>(gw1_w1,gw2_w1,se1_w1,se2_w1,
                                         gw1_b1,gw2_b1,se1_b1,se2_b1, flag, w1p, bp1);
  k_prep_gw<<<dim3(1152),256,0,stream>>>(gw1_w2, gw1_b2, flag, w2pg1, bpg);
  k_prep_gw<<<dim3(1152),256,0,stream>>>(gw2_w2, gw2_b2, flag, w2pg2, bpg+2304);
  k_prep_se<<<dim3(256),256,0,stream>>>(se1_w2, se2_w2, se1_b2, se2_b2, flag, w2ps, bps);
  k_prep_c<<<dim3(256),256,0,stream>>>(c1w, c1b, c3w, c3b, flag, c1wp, c1bp, c3wp, c3bp);
  k_seg_t<<<dim3(128,2),256,0,stream>>>(seg, flag, segt);
  k_x_t<<<dim3(128,2,4),256,0,stream>>>(x, flag, xt, part);   // + BN1 partial sums

  // branch conv1 (4 branches, relu) : segmap -> h1t[br]
  k_convgemm<64,9,1,3><<<dim3(128,4,2),256,0,stream>>>(
      segt, w1p, bp1, nullptr, h1t, 1,
      0L, 73728L, 128, 4326400L,
      1081600L, 8320, 8384,
      2163200L, 16640L, 128, 16768, 0L, 0,
      nullptr, nullptr, nullptr, nullptr);

  // se conv2 (2 branches, sigmoid) : h1t[2],h1t[3] -> sw1, sw2
  k_convgemm<128,9,2,3><<<dim3(128,4,2),256,0,stream>>>(
      h1t + 2*4326400L, w2ps, bps, nullptr, sw1, 2,
      4326400L, 294912L, 256, 8388608L,
      2163200L, 16640, 16768,
      4194304L, 32768L, 256, 0, 0L, 0,
      nullptr, nullptr, nullptr, nullptr);

  // BN1 stage 2 (stage 1 fused into k_x_t)
  k_bnstat2<<<dim3(1),256,0,stream>>>(part, bn1g, bn1b, flag, st1);

  // fused gw conv + BN1 + depthwise, branch 1: h1t[0] x xt -> dd
  k_convdw<<<dim3(128,16,2),256,0,stream>>>(h1t, w2pg1, bpg, xt, st1, dd);

  // 1x1 conv #1 (+bias, *sw1, lrelu) -> t1 (padded) + BN2 partial sums
  k_convgemm<256,1,3,3><<<dim3(128,2,2),256,0,stream>>>(
      dd, c1wp, c1bp, sw1, t1, 2,
      0L, 0L, 0, 0L,
      4194304L, 32768, 0,
      4326400L, 33280L, 256, 33536, 4194304L, 32768,
      nullptr, nullptr, nullptr, part);

  // BN2 stage 2
  k_bnstat2<<<dim3(1),256,0,stream>>>(part, bn2g, bn2b, flag, st2);

  // fused gw conv + BN2 + depthwise, branch 2: h1t[1] x t1 -> dd
  k_convdw<<<dim3(128,16,2),256,0,stream>>>(h1t + 4326400L, w2pg2, bpg+2304, t1, st2, dd);

  // 1x1 conv #2 (+bias, *sw2, lrelu) + fused residual add -> d_out (NCHW)
  k_convgemm<256,1,4,3><<<dim3(128,2,2),256,0,stream>>>(
      dd, c3wp, c3bp, sw2, dd, 2,
      0L, 0L, 0, 0L,
      4194304L, 32768, 0,
      0L, 0L, 256, 0, 4194304L, 32768,
      x, flag, d_out, nullptr);
}

// Round 16
// 577.878 us; speedup vs baseline: 1.3779x; 1.0255x over previous
//
#include <hip/hip_runtime.h>
#include <hip/hip_bf16.h>

typedef unsigned short u16;
typedef unsigned int u32;
typedef __attribute__((ext_vector_type(8))) short bf16x8;
typedef __attribute__((ext_vector_type(4))) float f32x4;
typedef __attribute__((address_space(3))) u32 lds_u32;
typedef const __attribute__((address_space(1))) u32 glb_u32;

#define H_ 128
#define W_ 128
#define PX 16384
#define PH 130

__device__ __forceinline__ float b2f(u16 h){ u32 u = ((u32)h)<<16; return __uint_as_float(u); }
__device__ __forceinline__ u16 f2b(float f){
  u32 u = __float_as_uint(f);
  u32 r = (u + 0x7fffu + ((u>>16)&1u)) >> 16;
  return (u16)r;
}
// mode: 1 = inputs are float32, 0 = inputs are bf16
__device__ __forceinline__ float ldv(const void* p, long i, int m){
  return m ? ((const float*)p)[i] : b2f(((const u16*)p)[i]);
}
__device__ __forceinline__ void gload16(const u16* g, u16* l){
  __builtin_amdgcn_global_load_lds((glb_u32*)g, (lds_u32*)l, 16, 0, 0);
}

// ---------------- dtype autodetect ----------------
__global__ void k_detect(const u32* __restrict__ xw, u32* __restrict__ flag){
  __shared__ int cnt[256];
  const int t = threadIdx.x;
  int c = 0;
  #pragma unroll
  for (int i=0;i<4;i++){
    const u32 w = xw[t*4+i];
    const u32 e = ((w & 0xFFFFu) >> 7) & 0xFF;
    if (e >= 90 && e <= 140) c++;     // bf16 low-half exponent range for N(0,1)
  }
  cnt[t] = c; __syncthreads();
  for (int s=128;s>0;s>>=1){ if (t<s) cnt[t]+=cnt[t+s]; __syncthreads(); }
  if (t==0) flag[0] = (cnt[0] < 512) ? 1u : 0u;   // few hits -> f32 data
}

// ---------------- border-zero for h1t pads ----------------
__global__ void k_zpad(u16* __restrict__ h1t){
  const int p = blockIdx.x;            // 8 planes: br = p>>1, n = p&1
  u16* base = h1t + (long)p*2163200L;  // [130][130][128]
  const int t = threadIdx.x;
  const int4 z = make_int4(0,0,0,0);
  for (int idx=t; idx<8256; idx+=256){
    long off;
    if (idx < 2080)       off = (long)idx*8;                                   // row 0
    else if (idx < 4160)  off = 2146560L + (long)(idx-2080)*8;                 // row 129
    else if (idx < 6208){ const int r = 1 + (idx-4160)/16, w = (idx-4160)%16;  // col 0
                          off = (long)r*16640 + w*8; }
    else {                const int r = 1 + (idx-6208)/16, w = (idx-6208)%16;  // col 129
                          off = (long)r*16640 + 16512 + w*8; }
    *(int4*)(base + off) = z;
  }
}

// ---------------- implicit-GEMM conv kernel (conv1 / se / 1x1) ----------------
// EPI: 0=bias, 1=bias+relu, 2=bias+sigmoid, 3=(bias)*sw+lrelu ->NHWC (+BN partial sums),
//      4=EPI3 math then fused residual add + NCHW write to outF
template<int CIN, int NTAPS, int EPI, int MINW>
__global__ __launch_bounds__(256, MINW)
void k_convgemm(const u16* __restrict__ inp, const u16* __restrict__ wp,
                const u16* __restrict__ bias, const u16* __restrict__ swp,
                u16* __restrict__ outp, int nbco,
                long in_br, long w_br, int bias_br, long out_br,
                long in_n, int in_row, int in_x0,
                long out_n, long out_y, int out_px, int out_x0,
                long sw_n, int sw_y,
                const void* __restrict__ xres, const u32* __restrict__ flagp,
                void* __restrict__ outF, float* __restrict__ partp)
{
  __shared__ u16 ls[17408];          // A:[0,8192) B:[8192,16384); epilogue tile [128][136]
  u16* lsA = ls;
  u16* lsB = ls + 8192;

  const int bx  = blockIdx.x;
  const int y   = (NTAPS==9) ? (((bx&7)<<4) | (bx>>3)) : bx;
  const int br  = blockIdx.y / nbco;
  const int cb  = blockIdx.y - br*nbco;
  const int n   = blockIdx.z;
  const int tid = threadIdx.x;
  const int wave = tid >> 6, lane = tid & 63;
  const int l16 = lane & 15, lg = lane >> 4;
  const int chw = (wave >> 1) * 64;   // co half
  const int phw = (wave & 1) * 64;    // px half

  const u16* inb   = inp + (long)br*in_br + (long)n*in_n + in_x0 + (long)y*in_row;
  const u16* wb    = wp  + (long)br*w_br + (long)cb*128*(NTAPS*CIN);
  const u16* biasb = bias + (long)br*bias_br + cb*128;
  u16* outb = outp + (long)br*out_br + (long)n*out_n + out_x0 + (long)y*out_y;

  f32x4 acc[4][4];
  #pragma unroll
  for (int m=0;m<4;m++)
    #pragma unroll
    for (int q=0;q<4;q++) acc[m][q] = (f32x4){0.f,0.f,0.f,0.f};

  const int NSTEP = NTAPS*(CIN/64);
  for (int step=0; step<NSTEP; ++step){
    const int tap = step/(CIN/64);
    const int k0  = (step - tap*(CIN/64))*64;
    const int dy = (NTAPS==1)?0:(tap/3-1);
    const int dx = (NTAPS==1)?0:(tap%3-1);
    const u16* wsrc = wb  + tap*CIN + k0;
    const u16* bsrc = inb + (long)dy*in_row + dx*CIN + k0;
    #pragma unroll
    for (int i=0;i<4;i++){
      const int idx = (wave*4+i)*64 + lane;
      const int r = idx>>3, c = idx&7;
      const int cc = c ^ (r&7);
      gload16(wsrc + (long)r*(NTAPS*CIN) + cc*8, lsA + (wave*4+i)*512);
    }
    #pragma unroll
    for (int i=0;i<4;i++){
      const int idx = (wave*4+i)*64 + lane;
      const int r = idx>>3, c = idx&7;
      const int cc = c ^ (r&7);
      gload16(bsrc + (long)r*CIN + cc*8, lsB + (wave*4+i)*512);
    }
    __syncthreads();
    #pragma unroll
    for (int kk=0;kk<2;kk++){
      bf16x8 af[4], bfr[4];
      const int kc = kk*4 + lg;
      #pragma unroll
      for (int m=0;m<4;m++){
        const int r = chw + m*16 + l16;
        af[m] = *(const bf16x8*)(lsA + r*64 + ((kc ^ (r&7))<<3));
      }
      #pragma unroll
      for (int q=0;q<4;q++){
        const int r = phw + q*16 + l16;
        bfr[q] = *(const bf16x8*)(lsB + r*64 + ((kc ^ (r&7))<<3));
      }
      #pragma unroll
      for (int m=0;m<4;m++)
        #pragma unroll
        for (int q=0;q<4;q++)
          acc[m][q] = __builtin_amdgcn_mfma_f32_16x16x32_bf16(af[m], bfr[q], acc[m][q], 0,0,0);
    }
    __syncthreads();
  }

  // epilogue: acc -> LDS tile [px 128][co 136]
  #pragma unroll
  for (int m=0;m<4;m++){
    const int co = chw + m*16 + lg*4;
    const ushort4 bb = *(const ushort4*)(biasb + co);
    const float bv0=b2f(bb.x), bv1=b2f(bb.y), bv2=b2f(bb.z), bv3=b2f(bb.w);
    #pragma unroll
    for (int q=0;q<4;q++){
      const int px = phw + q*16 + l16;
      float v0 = acc[m][q][0] + bv0;
      float v1 = acc[m][q][1] + bv1;
      float v2 = acc[m][q][2] + bv2;
      float v3 = acc[m][q][3] + bv3;
      if (EPI==1){
        v0=fmaxf(v0,0.f); v1=fmaxf(v1,0.f); v2=fmaxf(v2,0.f); v3=fmaxf(v3,0.f);
      } else if (EPI==2){
        v0 = 1.f/(1.f+__expf(-v0)); v1 = 1.f/(1.f+__expf(-v1));
        v2 = 1.f/(1.f+__expf(-v2)); v3 = 1.f/(1.f+__expf(-v3));
      } else if (EPI==3 || EPI==4){
        const ushort4 sv = *(const ushort4*)(swp + (long)n*sw_n + (long)y*sw_y + (long)px*256 + cb*128 + co);
        v0 *= b2f(sv.x); v1 *= b2f(sv.y); v2 *= b2f(sv.z); v3 *= b2f(sv.w);
        v0 = v0>=0.f? v0 : 0.2f*v0;  v1 = v1>=0.f? v1 : 0.2f*v1;
        v2 = v2>=0.f? v2 : 0.2f*v2;  v3 = v3>=0.f? v3 : 0.2f*v3;
      }
      ushort4 ov; ov.x=f2b(v0); ov.y=f2b(v1); ov.z=f2b(v2); ov.w=f2b(v3);
      *(ushort4*)(ls + px*136 + co) = ov;
    }
  }
  __syncthreads();
  if (EPI == 4){
    const int m2 = (int)flagp[0];
    const int co = tid>>1, hf2 = tid&1;
    const long xoff = (((long)n*256 + cb*128 + co)*H_ + y)*W_ + hf2*64;
    const u16* lrow = ls + (hf2*64)*136 + co;
    if (m2){
      const float* xf = (const float*)xres;
      float* of = (float*)outF;
      #pragma unroll
      for (int i=0;i<16;i++){
        const float4 xv = *(const float4*)(xf + xoff + i*4);
        float4 ov;
        ov.x = xv.x + b2f(lrow[(i*4+0)*136]);
        ov.y = xv.y + b2f(lrow[(i*4+1)*136]);
        ov.z = xv.z + b2f(lrow[(i*4+2)*136]);
        ov.w = xv.w + b2f(lrow[(i*4+3)*136]);
        *(float4*)(of + xoff + i*4) = ov;
      }
    } else {
      const u16* xu = (const u16*)xres;
      u16* ou = (u16*)outF;
      #pragma unroll
      for (int i=0;i<8;i++){
        const bf16x8 xv = *(const bf16x8*)(xu + xoff + i*8);
        bf16x8 ov;
        #pragma unroll
        for (int e=0;e<8;e++)
          ov[e] = (short)f2b(b2f((u16)xv[e]) + b2f(lrow[(i*8+e)*136]));
        *(bf16x8*)(ou + xoff + i*8) = ov;
      }
    }
  } else {
    const int row = tid>>1, hf = tid&1;
    u16* og = outb + (long)row*out_px + cb*128 + hf*64;
    #pragma unroll
    for (int i=0;i<8;i++)
      *(int4*)(og + i*8) = *(const int4*)(ls + row*136 + hf*64 + i*8);
    if (EPI == 3){
      if (tid < 128){
        const int co = tid;
        float s = 0.f, q = 0.f;
        for (int px=0; px<128; ++px){
          const float v = b2f(ls[px*136 + co]);
          s += v; q += v*v;
        }
        const int cidx = cb*128 + co, w = n*128 + y;
        partp[(long)cidx*256 + w] = s;
        partp[65536L + (long)cidx*256 + w] = q;
      }
    }
  }
}

// ---------------- FUSED gw-conv + BN-affine + dynamic depthwise ----------------
// v6 + xh LDS tile + HOISTED invariant staging offsets (r16): the per-thread swizzle
// offsets for the 9 staging slots are loop-invariant -> precompute into registers,
// leaving ~2 SALU + 9 v_add per K-step instead of ~60 VALU. Gate: VGPR <= 98.
__global__ __launch_bounds__(256, 2)
void k_convdw(const u16* __restrict__ h1,      // padded [n][130][130][128]
              const u16* __restrict__ wp,      // [2304][9][128]
              const u16* __restrict__ bp,      // [2304] (co''=c*9+k order)
              const u16* __restrict__ xh,      // padded [n][130][130][256] (pre-BN act)
              const float2* __restrict__ ss,   // BN (scale, shift)
              u16* __restrict__ dd)            // [n][16384][256]
{
  __shared__ u16 ls[25248];   // staging A[0,9216) B[9216,17408); ct[144][132]=[0,19008); xh[19008,25248)
  u16* lsA = ls;
  u16* lsB = ls + 9216;
  u16* xtile = ls + 19008;    // [3][130][16]

  const int bx = blockIdx.x, mt = blockIdx.y, n = blockIdx.z;   // mt in [0,16)
  const int y = ((bx&7)<<4) | (bx>>3);      // XCD-band swizzle (bijective, 128%8==0)
  const int tid = threadIdx.x;
  const int wave = tid >> 6, lane = tid & 63;
  const int l16 = lane & 15, lg = lane >> 4;
  const int wn = wave * 32;           // px offset of wave

  const u16* wb = wp + (long)mt*144*1152;
  const u16* inb = h1 + (((long)n*PH + (y+1))*PH + 1)*128;

  // ---- hoisted invariant per-thread staging offsets ----
  int aoffg[5], boffg[4], offl[5];
  #pragma unroll
  for (int i=0;i<4;i++){
    const int g = i*256 + tid;
    const int r = g>>3, c = g&7;
    aoffg[i] = r*1152 + (c ^ (r&7))*8;
    const int p = g>>3;
    boffg[i] = p*128 + (c ^ (p&7))*8;
    offl[i] = g*8;
  }
  {
    const int g = 1024 + tid;     // A slot 5, tid<128 only
    const int r = g>>3, c = g&7;
    aoffg[4] = r*1152 + (c ^ (r&7))*8;
    offl[4] = g*8;
  }

  // pre-issue xh halo tile loads: rows y-1..y+1 (padded y..y+2), 130 x, 16 ch
  {
    const u16* xb = xh + ((long)n*PH + y)*PH*256 + mt*16;
    #pragma unroll
    for (int i=0;i<4;i++){
      const int q = i*256 + tid;          // 780 chunks of 16B
      if (q < 780){
        const int h = q & 1, pos = q >> 1;
        const int r = pos/130, xx = pos - r*130;
        gload16(xb + ((long)r*PH + xx)*256 + h*8, xtile + q*8);
      }
    }
  }

  f32x4 acc[9][2];
  #pragma unroll
  for (int m=0;m<9;m++){ acc[m][0]=(f32x4){0,0,0,0}; acc[m][1]=(f32x4){0,0,0,0}; }

  for (int s=0; s<18; ++s){
    const int tap = s >> 1;
    const int k0  = (s & 1) * 64;
    const int dy = tap/3 - 1, dx = tap%3 - 1;
    const u16* wsrc = wb + tap*128 + k0;
    const u16* bsrc = inb + ((long)dy*PH + dx)*128 + k0;
    // stage A: 144 rows x 64 ci = 1152 chunks (4 x 256 + 128)
    #pragma unroll
    for (int i=0;i<4;i++)
      gload16(wsrc + aoffg[i], lsA + offl[i]);
    if (tid < 128)
      gload16(wsrc + aoffg[4], lsA + offl[4]);
    // stage B: 128 px x 64 ci = 1024 chunks (4 x 256)
    #pragma unroll
    for (int i=0;i<4;i++)
      gload16(bsrc + boffg[i], lsB + offl[i]);
    __syncthreads();
    #pragma unroll
    for (int kk=0;kk<2;kk++){
      const int kc = kk*4 + lg;
      bf16x8 bfr[2];
      #pragma unroll
      for (int q=0;q<2;q++){
        const int rb = wn + q*16 + l16;
        bfr[q] = *(const bf16x8*)(lsB + rb*64 + ((kc ^ (rb&7))<<3));
      }
      #pragma unroll
      for (int m=0;m<9;m++){
        const int ra = m*16 + l16;
        const bf16x8 a = *(const bf16x8*)(lsA + ra*64 + ((kc ^ (ra&7))<<3));
        acc[m][0] = __builtin_amdgcn_mfma_f32_16x16x32_bf16(a, bfr[0], acc[m][0], 0,0,0);
        acc[m][1] = __builtin_amdgcn_mfma_f32_16x16x32_bf16(a, bfr[1], acc[m][1], 0,0,0);
      }
    }
    __syncthreads();
  }

  // ---- epilogue 1: cw + bias -> ct[144][132] (all 4 waves, disjoint px) ----
  u16* ct = ls;
  #pragma unroll
  for (int m=0;m<9;m++){
    const int r0 = m*16 + lg*4;
    const ushort4 bb = *(const ushort4*)(bp + mt*144 + r0);
    const float bv0=b2f(bb.x), bv1=b2f(bb.y), bv2=b2f(bb.z), bv3=b2f(bb.w);
    #pragma unroll
    for (int q=0;q<2;q++){
      const int px = wn + q*16 + l16;
      ct[(r0+0)*132 + px] = f2b(acc[m][q][0] + bv0);
      ct[(r0+1)*132 + px] = f2b(acc[m][q][1] + bv1);
      ct[(r0+2)*132 + px] = f2b(acc[m][q][2] + bv2);
      ct[(r0+3)*132 + px] = f2b(acc[m][q][3] + bv3);
    }
  }
  __syncthreads();

  // ---- epilogue 2: depthwise from LDS. cl = tid&15 channel, xg = tid>>4 ----
  const int cl = tid & 15;
  const int c  = mt*16 + cl;
  const float2 sc = ss[c];
  const int xg = tid >> 4;
  #pragma unroll
  for (int i=0;i<8;i++){
    const int x = i*16 + xg;
    float a = 0.f;
    #pragma unroll
    for (int k=0;k<9;k++){
      const int ddy = k/3-1, ddx = k%3-1;
      const int gy = y+ddy, gx = x+ddx;
      if ((unsigned)gy < 128u && (unsigned)gx < 128u){
        const float xv = b2f(xtile[((ddy+1)*130 + (gx+1))*16 + cl]);
        const float w  = b2f(ct[(cl*9+k)*132 + x]);
        a += (xv*sc.x + sc.y) * w;
      }
    }
    dd[(((long)n*PX) + (long)y*W_ + x)*256 + c] = f2b(a);
  }
}

// ---------------- BN stage 2 (stage 1 fused into producers; part = [c][w] + sq at +65536) ----------------
__global__ void k_bnstat2(const float* __restrict__ part, const void* __restrict__ g,
                          const void* __restrict__ b, const u32* __restrict__ flag,
                          float2* __restrict__ st)
{
  const int m = (int)flag[0];
  const int c = threadIdx.x;
  float s=0.f,q=0.f;
  for (int w=0;w<256;w++){ s += part[(long)c*256 + w]; q += part[65536L + (long)c*256 + w]; }
  const float mean = s*(1.f/32768.f);
  float v = q*(1.f/32768.f) - mean*mean;
  v = fmaxf(v, 0.f);
  const float sc = ldv(g,c,m) / sqrtf(v + 1e-5f);
  st[c] = make_float2(sc, ldv(b,c,m) - mean*sc);
}

// ---------------- merged weight prepack (gw x2 | se | w1 | c) ----------------
// grid 3968: [0,2304) gw (brn=blk/1152); [2304,2560) se; [2560,3712) w1; [3712,3968) c
__global__ void k_prep_all(const void* gw1_w2, const void* gw1_b2,
                           const void* gw2_w2, const void* gw2_b2,
                           const void* se1_w2, const void* se2_w2,
                           const void* se1_b2, const void* se2_b2,
                           const void* w1a, const void* w1b, const void* w1c, const void* w1d,
                           const void* b1a, const void* b1b, const void* b1c, const void* b1d,
                           const void* c1w, const void* c1b, const void* c3w, const void* c3b,
                           const u32* __restrict__ flag,
                           u16* w2pg1, u16* w2pg2, u16* bpg,
                           u16* w2ps, u16* bps,
                           u16* w1p, u16* bp1,
                           u16* c1wp, u16* c1bp, u16* c3wp, u16* c3bp)
{
  __shared__ u16 lt[2304];
  const int m = (int)flag[0];
  const int blk = blockIdx.x;
  const int t = threadIdx.x;
  if (blk < 2304){
    // gw: native [co''][ci 128][tap 9] -> [co''][tap][ci], coalesced via LDS
    const int brn = blk / 1152, b = blk - brn*1152;
    const void* w2 = brn ? gw2_w2 : gw1_w2;
    u16* w2p = brn ? w2pg2 : w2pg1;
    #pragma unroll
    for (int i=0;i<9;i++){
      const int g = i*256 + t;
      const long src = (long)b*2304 + g;
      const int lco = g/1152, rem = g - lco*1152;
      const int ci = rem/9, tap = rem - ci*9;
      lt[lco*1152 + tap*128 + ci] = f2b(ldv(w2, src, m));
    }
    __syncthreads();
    #pragma unroll
    for (int i=0;i<9;i++){
      const int g = i*256 + t;
      w2p[(long)b*2304 + g] = lt[g];
    }
    if (b < 9){
      const int bi = b*256 + t;
      if (bi < 2304) (brn ? bpg+2304 : bpg)[bi] = f2b(ldv(brn?gw2_b2:gw1_b2, bi, m));
    }
  } else if (blk < 2560){
    // se: per branch native [co 256][ci 128][tap 9] -> [brn][co][tap][ci]
    const int b = blk - 2304;          // [0,256)
    const int brn = b >> 7;
    const void* w = brn ? se2_w2 : se1_w2;
    #pragma unroll
    for (int i=0;i<9;i++){
      const int g = i*256 + t;
      const long src = (long)(b&127)*2304 + g;
      const int lco = g/1152, rem = g - lco*1152;
      const int ci = rem/9, tap = rem - ci*9;
      lt[lco*1152 + tap*128 + ci] = f2b(ldv(w, src, m));
    }
    __syncthreads();
    #pragma unroll
    for (int i=0;i<9;i++){
      const int g = i*256 + t;
      w2ps[(long)b*2304 + g] = lt[g];
    }
    if ((b & 127) == 0)
      bps[brn*256 + t] = f2b(ldv(brn?se2_b2:se1_b2, t, m));
  } else if (blk < 3712){
    const int idx = (blk-2560)*256 + t;   // 294912 = 4*128*9*64
    {
      const int ci = idx & 63, r = (idx>>6)%9, co = (idx/576)%128, brn = idx/73728;
      const void* w = brn==0?w1a:brn==1?w1b:brn==2?w1c:w1d;
      u16 v = 0;
      if (ci < 35) v = f2b(ldv(w, ((long)co*35 + ci)*9 + r, m));
      w1p[idx] = v;
    }
    if (idx < 512){
      const int brn = idx>>7, co = idx&127;
      const void* bb2 = brn==0?b1a:brn==1?b1b:brn==2?b1c:b1d;
      bp1[idx] = f2b(ldv(bb2, co, m));
    }
  } else {
    const int idx = (blk-3712)*256 + t;   // 65536
    c1wp[idx] = f2b(ldv(c1w, idx, m));
    c3wp[idx] = f2b(ldv(c3w, idx, m));
    if (idx < 256){
      c1bp[idx] = f2b(ldv(c1b, idx, m));
      c3bp[idx] = f2b(ldv(c3b, idx, m));
    }
  }
}

// ---------------- input transposes (mode-aware) ----------------
__global__ __launch_bounds__(256)
void k_seg_t(const void* __restrict__ seg, const u32* __restrict__ flag,
             u16* __restrict__ segt)
{
  __shared__ u16 lt[8192];     // [x 128][ci 64]
  const int m = (int)flag[0];
  const int y = blockIdx.x, n = blockIdx.y, t = threadIdx.x;
  for (int i=t;i<8192;i+=256) lt[i]=0;
  __syncthreads();
  for (int idx=t; idx<128*35; idx+=256){
    const int x = idx/35, ci = idx - x*35;
    lt[x*64+ci] = f2b(ldv(seg, (((long)n*35 + ci)*256 + 2*y)*256 + 2*x, m));
  }
  __syncthreads();
  const int x = t>>1, hf = t&1;
  u16* o = segt + (((long)n*PH + (y+1))*PH + (x+1))*64 + hf*32;
  #pragma unroll
  for (int i=0;i<4;i++) *(int4*)(o + i*8) = *(const int4*)&lt[x*64 + hf*32 + i*8];
}

// x NCHW -> padded NHWC + fused BN1 partial sums; grid (128 y, 2 n, 4 cb)
__global__ __launch_bounds__(256)
void k_x_t(const void* __restrict__ x, const u32* __restrict__ flag,
           u16* __restrict__ xt, float* __restrict__ part)
{
  __shared__ u16 lt[128*72];
  const int m = (int)flag[0];
  const int y = blockIdx.x, n = blockIdx.y, cb = blockIdx.z;
  const int t = threadIdx.x;
  const long base = ((long)n*256 + cb*64)*PX + (long)y*W_;
  if (m){
    const float* xf = (const float*)x + base;
    #pragma unroll
    for (int i=0;i<8;i++){
      const int q = i*256 + t;          // 2048 float4
      const int c = q>>5, x4 = (q&31)*4;
      const float4 v = *(const float4*)(xf + (long)c*PX + x4);
      lt[(x4+0)*72 + c] = f2b(v.x);
      lt[(x4+1)*72 + c] = f2b(v.y);
      lt[(x4+2)*72 + c] = f2b(v.z);
      lt[(x4+3)*72 + c] = f2b(v.w);
    }
  } else {
    const u16* xu = (const u16*)x + base;
    #pragma unroll
    for (int i=0;i<4;i++){
      const int q = i*256 + t;          // 1024 ushort8
      const int c = q>>4, x8 = (q&15)*8;
      const bf16x8 v = *(const bf16x8*)(xu + (long)c*PX + x8);
      #pragma unroll
      for (int e=0;e<8;e++) lt[(x8+e)*72 + c] = (u16)v[e];
    }
  }
  __syncthreads();
  const int xx = t>>1, hf = t&1;
  u16* o = xt + (((long)n*PH + (y+1))*PH + (xx+1))*256 + cb*64 + hf*32;
  #pragma unroll
  for (int i=0;i<4;i++) *(int4*)(o+i*8) = *(const int4*)&lt[xx*72 + hf*32 + i*8];
  // fused BN1 partial sums; part layout [c 256][w 256] (+65536 for sq)
  if (t < 64){
    float s = 0.f, q = 0.f;
    for (int xi=0; xi<128; ++xi){
      const float v = b2f(lt[xi*72 + t]);
      s += v; q += v*v;
    }
    const int cidx = cb*64 + t, w = n*128 + y;
    part[(long)cidx*256 + w] = s;
    part[65536L + (long)cidx*256 + w] = q;
  }
}

extern "C" void kernel_launch(void* const* d_in, const int* in_sizes, int n_in,
                              void* d_out, int out_size, void* d_ws, size_t ws_size,
                              hipStream_t stream)
{
  (void)in_sizes; (void)n_in; (void)out_size; (void)ws_size;
  const void* x      = d_in[0];
  const void* seg    = d_in[1];
  const void* gw1_w1 = d_in[2];
  const void* gw1_b1 = d_in[3];
  const void* gw1_w2 = d_in[4];
  const void* gw1_b2 = d_in[5];
  const void* gw2_w1 = d_in[6];
  const void* gw2_b1 = d_in[7];
  const void* gw2_w2 = d_in[8];
  const void* gw2_b2 = d_in[9];
  const void* se1_w1 = d_in[10];
  const void* se1_b1 = d_in[11];
  const void* se1_w2 = d_in[12];
  const void* se1_b2 = d_in[13];
  const void* se2_w1 = d_in[14];
  const void* se2_b1 = d_in[15];
  const void* se2_w2 = d_in[16];
  const void* se2_b2 = d_in[17];
  const void* c1w = d_in[18];
  const void* c1b = d_in[19];
  const void* c3w = d_in[20];
  const void* c3b = d_in[21];
  const void* bn1g = d_in[22];
  const void* bn1b = d_in[23];
  const void* bn2g = d_in[24];
  const void* bn2b = d_in[25];
  u16* ws = (u16*)d_ws;

  // workspace layout (u16 element offsets), peak = 59,882,112 u16 = 119.8 MB
  u16* segt  = ws;                       // 2,163,200
  u16* xt    = ws + 2163200L;            // 8,652,800  (= t1, serialized overlay)
  u16* t1    = xt;
  u16* dd    = ws + 10816000L;           // 8,388,608
  u16* sw1   = ws + 19204608L;           // 8,388,608
  u16* sw2   = ws + 27593216L;           // 8,388,608
  u16* w1p   = ws + 35981824L;           // 294,912
  u16* bp1   = ws + 36276736L;           // 512
  u16* w2pg1 = ws + 36277248L;           // 2,654,208
  u16* w2pg2 = ws + 38931456L;           // 2,654,208
  u16* bpg   = ws + 41585664L;           // 4,608
  u16* w2ps  = ws + 41590272L;           // 589,824
  u16* bps   = ws + 42180096L;           // 512
  u16* c1wp  = ws + 42180608L;           // 65,536
  u16* c1bp  = ws + 42246144L;           // 256
  u16* c3wp  = ws + 42246400L;           // 65,536
  u16* c3bp  = ws + 42311936L;           // 256
  float*  part = (float*)(ws + 42312192L);   // 131,072 f32 (262,144 u16)
  float2* st1  = (float2*)(ws + 42574336L);  // 256 float2 (1,024 u16)
  float2* st2  = (float2*)(ws + 42575360L);  // 256 float2 (1,024 u16)
  u32*    flag = (u32*)(ws + 42576384L);     // 1 u32 (+pad)
  u16* h1t   = ws + 42576512L;           // 17,305,600 [4 branches x 2*130*130*128]

  // zero pads: segt memset (small) + h1t border-only kernel
  hipMemsetAsync(segt, 0, 4326400ULL, stream);
  k_zpad<<<dim3(8),256,0,stream>>>(h1t);

  // dtype autodetect, then merged prepack + transposes
  k_detect<<<dim3(1),256,0,stream>>>((const u32*)x, flag);
  k_prep_all<<<dim3(3968),256,0,stream>>>(
      gw1_w2, gw1_b2, gw2_w2, gw2_b2,
      se1_w2, se2_w2, se1_b2, se2_b2,
      gw1_w1, gw2_w1, se1_w1, se2_w1,
      gw1_b1, gw2_b1, se1_b1, se2_b1,
      c1w, c1b, c3w, c3b, flag,
      w2pg1, w2pg2, bpg, w2ps, bps, w1p, bp1, c1wp, c1bp, c3wp, c3bp);
  k_seg_t<<<dim3(128,2),256,0,stream>>>(seg, flag, segt);
  k_x_t<<<dim3(128,2,4),256,0,stream>>>(x, flag, xt, part);   // + BN1 partial sums

  // branch conv1 (4 branches, relu) : segmap -> h1t[br]
  k_convgemm<64,9,1,3><<<dim3(128,4,2),256,0,stream>>>(
      segt, w1p, bp1, nullptr, h1t, 1,
      0L, 73728L, 128, 4326400L,
      1081600L, 8320, 8384,
      2163200L, 16640L, 128, 16768, 0L, 0,
      nullptr, nullptr, nullptr, nullptr);

  // se conv2 (2 branches, sigmoid) : h1t[2],h1t[3] -> sw1, sw2
  k_convgemm<128,9,2,3><<<dim3(128,4,2),256,0,stream>>>(
      h1t + 2*4326400L, w2ps, bps, nullptr, sw1, 2,
      4326400L, 294912L, 256, 8388608L,
      2163200L, 16640, 16768,
      4194304L, 32768L, 256, 0, 0L, 0,
      nullptr, nullptr, nullptr, nullptr);

  // BN1 stage 2 (stage 1 fused into k_x_t)
  k_bnstat2<<<dim3(1),256,0,stream>>>(part, bn1g, bn1b, flag, st1);

  // fused gw conv + BN1 + depthwise, branch 1: h1t[0] x xt -> dd
  k_convdw<<<dim3(128,16,2),256,0,stream>>>(h1t, w2pg1, bpg, xt, st1, dd);

  // 1x1 conv #1 (+bias, *sw1, lrelu) -> t1 (padded) + BN2 partial sums
  k_convgemm<256,1,3,3><<<dim3(128,2,2),256,0,stream>>>(
      dd, c1wp, c1bp, sw1, t1, 2,
      0L, 0L, 0, 0L,
      4194304L, 32768, 0,
      4326400L, 33280L, 256, 33536, 4194304L, 32768,
      nullptr, nullptr, nullptr, part);

  // BN2 stage 2
  k_bnstat2<<<dim3(1),256,0,stream>>>(part, bn2g, bn2b, flag, st2);

  // fused gw conv + BN2 + depthwise, branch 2: h1t[1] x t1 -> dd
  k_convdw<<<dim3(128,16,2),256,0,stream>>>(h1t + 4326400L, w2pg2, bpg+2304, t1, st2, dd);

  // 1x1 conv #2 (+bias, *sw2, lrelu) + fused residual add -> d_out (NCHW)
  k_convgemm<256,1,4,3><<<dim3(128,2,2),256,0,stream>>>(
      dd, c3wp, c3bp, sw2, dd, 2,
      0L, 0L, 0, 0L,
      4194304L, 32768, 0,
      0L, 0L, 256, 0, 4194304L, 32768,
      x, flag, d_out, nullptr);
}